// Round 1
// baseline (2022.836 us; speedup 1.0000x reference)
//
#include <hip/hip_runtime.h>
#include <math.h>

#define Nn 50000
#define Ee 800000
#define ETe 850000   // E + N self loops
#define Dd 64
#define FIN 128
#define LL 8

// ---------------- graph build ----------------

__global__ __launch_bounds__(256) void k_deg(const int* __restrict__ ei, int* __restrict__ deg) {
  int e = blockIdx.x * 256 + threadIdx.x;
  if (e >= ETe) return;
  int dst = (e < Ee) ? ei[Ee + e] : (e - Ee);
  atomicAdd(&deg[dst], 1);
}

__global__ __launch_bounds__(1024) void k_scan(const int* __restrict__ deg, int* __restrict__ rowptr) {
  __shared__ int wsum[16];
  int tid = threadIdx.x;
  int lane = tid & 63, wid = tid >> 6;
  int carry = 0;
  for (int base = 0; base < Nn; base += 1024) {
    int i = base + tid;
    int v = (i < Nn) ? deg[i] : 0;
    int s = v;
    #pragma unroll
    for (int off = 1; off < 64; off <<= 1) {
      int t = __shfl_up(s, off, 64);
      if (lane >= off) s += t;
    }
    if (lane == 63) wsum[wid] = s;
    __syncthreads();
    if (wid == 0) {
      int ws = (lane < 16) ? wsum[lane] : 0;
      #pragma unroll
      for (int off = 1; off < 16; off <<= 1) {
        int t = __shfl_up(ws, off, 64);
        if (lane >= off) ws += t;
      }
      if (lane < 16) wsum[lane] = ws;
    }
    __syncthreads();
    int wexcl = (wid == 0) ? 0 : wsum[wid - 1];
    if (i < Nn) rowptr[i + 1] = carry + wexcl + s;
    carry += wsum[15];
    __syncthreads();
  }
  if (tid == 0) rowptr[0] = 0;
}

__global__ __launch_bounds__(256) void k_dinv(const int* __restrict__ rowptr, float* __restrict__ dinv) {
  int n = blockIdx.x * 256 + threadIdx.x;
  if (n >= Nn) return;
  int d = rowptr[n + 1] - rowptr[n];   // >= 1 (self loop)
  dinv[n] = rsqrtf((float)d);
}

__global__ __launch_bounds__(256) void k_fill(const int* __restrict__ ei, const int* __restrict__ rowptr,
                                              int* __restrict__ fill, const float* __restrict__ dinv,
                                              int* __restrict__ col, float* __restrict__ en) {
  int e = blockIdx.x * 256 + threadIdx.x;
  if (e >= ETe) return;
  int src, dst;
  if (e < Ee) { src = ei[e]; dst = ei[Ee + e]; }
  else { src = e - Ee; dst = src; }
  int pos = rowptr[dst] + atomicAdd(&fill[dst], 1);
  col[pos] = src;
  en[pos] = dinv[src] * dinv[dst];
}

// ---------------- learner MLP (per-wave, 64 lanes = 64 channels) ----------------

__device__ __forceinline__ float learner_sig(float hm, const float4 w1, const float4 lb1v,
                                             const float4 l2, float lb2v) {
  float p0 = hm * w1.x, p1 = hm * w1.y, p2 = hm * w1.z, p3 = hm * w1.w;
  #pragma unroll
  for (int off = 32; off > 0; off >>= 1) {
    p0 += __shfl_xor(p0, off, 64);
    p1 += __shfl_xor(p1, off, 64);
    p2 += __shfl_xor(p2, off, 64);
    p3 += __shfl_xor(p3, off, 64);
  }
  float z0 = p0 + lb1v.x; z0 = z0 > 0.f ? z0 : 0.2f * z0;
  float z1 = p1 + lb1v.y; z1 = z1 > 0.f ? z1 : 0.2f * z1;
  float z2 = p2 + lb1v.z; z2 = z2 > 0.f ? z2 : 0.2f * z2;
  float z3 = p3 + lb1v.w; z3 = z3 > 0.f ? z3 : 0.2f * z3;
  float lg = z0 * l2.x + z1 * l2.y + z2 * l2.z + z3 * l2.w + lb2v;
  return 1.f / (1.f + expf(-lg));
}

// ---------------- input map ----------------

// t = x @ W1 + b1, with per-block BN partial sums (per column)
__global__ __launch_bounds__(256) void k_ingemm(const float* __restrict__ x,
    const float* __restrict__ W1, const float* __restrict__ b1,
    float* __restrict__ t, float* __restrict__ pS, float* __restrict__ pQ) {
  __shared__ float xs[32 * FIN];
  __shared__ float ws[64 * FIN];
  int tid = threadIdx.x;
  int row0 = blockIdx.x * 32;
  for (int i = tid; i < 32 * FIN; i += 256) {
    int r = i >> 7, c = i & 127;
    int gr = row0 + r;
    xs[i] = (gr < Nn) ? x[(size_t)gr * FIN + c] : 0.f;
  }
  int colc = tid & 127;
  int rp = tid >> 7;   // 0..1
  float acc[16];
  #pragma unroll
  for (int i = 0; i < 16; ++i) acc[i] = 0.f;
  for (int kc = 0; kc < 2; ++kc) {
    __syncthreads();
    for (int i = tid; i < 64 * FIN; i += 256) ws[i] = W1[kc * 64 * FIN + i];
    __syncthreads();
    for (int k = 0; k < 64; ++k) {
      float wv = ws[k * FIN + colc];
      #pragma unroll
      for (int rr = 0; rr < 16; ++rr)
        acc[rr] = fmaf(xs[(rr * 2 + rp) * FIN + kc * 64 + k], wv, acc[rr]);
    }
  }
  float bv = b1[colc];
  float s = 0.f, q = 0.f;
  #pragma unroll
  for (int rr = 0; rr < 16; ++rr) {
    int gr = row0 + rr * 2 + rp;
    if (gr < Nn) {
      float v = acc[rr] + bv;
      t[(size_t)gr * FIN + colc] = v;
      s += v; q += v * v;
    }
  }
  __syncthreads();
  xs[tid] = s; xs[256 + tid] = q;
  __syncthreads();
  if (rp == 0) {
    float st = xs[colc] + xs[128 + colc];
    float qt = xs[256 + colc] + xs[384 + colc];
    pS[blockIdx.x * FIN + colc] = st;
    pQ[blockIdx.x * FIN + colc] = qt;
  }
}

// reduce per-block partials -> scale/shift for BN
__global__ __launch_bounds__(1024) void k_finalize(const float* __restrict__ pS, const float* __restrict__ pQ,
    int nblk, int nch, const float* __restrict__ gamma, const float* __restrict__ beta,
    float* __restrict__ scaleA, float* __restrict__ shiftA) {
  __shared__ float ls[1024], lq[1024];
  int tid = threadIdx.x;
  int ch = tid % nch, sl = tid / nch, nsl = 1024 / nch;
  float s = 0.f, q = 0.f;
  for (int b = sl; b < nblk; b += nsl) { s += pS[b * nch + ch]; q += pQ[b * nch + ch]; }
  ls[tid] = s; lq[tid] = q;
  __syncthreads();
  if (sl == 0) {
    for (int t2 = 1; t2 < nsl; ++t2) { s += ls[t2 * nch + ch]; q += lq[t2 * nch + ch]; }
    float mu = s / (float)Nn;
    float var = q / (float)Nn - mu * mu;
    float rs = rsqrtf(var + 1e-5f);
    float scv = gamma[ch] * rs;
    scaleA[ch] = scv;
    shiftA[ch] = beta[ch] - mu * scv;
  }
}

// h = relu(bn(t)) @ W2 + b2 ; learner0 ; fused = h
__global__ __launch_bounds__(256) void k_inmap2(
    const float* __restrict__ t, const float* __restrict__ W2, const float* __restrict__ b2,
    const float* __restrict__ scaleA, const float* __restrict__ shiftA,
    const float* __restrict__ lw1p, const float* __restrict__ lb1p,
    const float* __restrict__ lw2p, const float* __restrict__ lb2p,
    float* __restrict__ h, float* __restrict__ fused) {
  __shared__ float ws[FIN * Dd];
  __shared__ float rb[4 * FIN];
  int tid = threadIdx.x, lane = tid & 63, wid = tid >> 6;
  for (int i = tid; i < FIN * Dd; i += 256) ws[i] = W2[i];
  __syncthreads();
  float4 w1 = reinterpret_cast<const float4*>(lw1p)[lane];
  float4 lb1v = *reinterpret_cast<const float4*>(lb1p);
  float4 l2 = *reinterpret_cast<const float4*>(lw2p);
  float lb2v = lb2p[0];
  float sc0 = scaleA[lane], sh0 = shiftA[lane];
  float sc1 = scaleA[64 + lane], sh1 = shiftA[64 + lane];
  float bv = b2[lane];
  int nw = gridDim.x * 4;
  for (int row = blockIdx.x * 4 + wid; row < Nn; row += nw) {
    float v0 = t[(size_t)row * FIN + lane];
    float v1 = t[(size_t)row * FIN + 64 + lane];
    v0 = fmaxf(fmaf(v0, sc0, sh0), 0.f);
    v1 = fmaxf(fmaf(v1, sc1, sh1), 0.f);
    rb[wid * FIN + lane] = v0;
    rb[wid * FIN + 64 + lane] = v1;
    float acc = bv;
    #pragma unroll 16
    for (int k = 0; k < FIN; ++k) acc = fmaf(rb[wid * FIN + k], ws[k * Dd + lane], acc);
    float sgm = learner_sig(acc, w1, lb1v, l2, lb2v);
    float hn = acc * sgm;
    h[(size_t)row * Dd + lane] = hn;
    fused[(size_t)row * Dd + lane] = hn;
  }
}

// ---------------- per-layer kernels ----------------

__global__ __launch_bounds__(256) void k_gemm64(const float* __restrict__ h,
    const float* __restrict__ W, float* __restrict__ m) {
  __shared__ float ws[Dd * Dd];
  __shared__ float rb[4 * Dd];
  int tid = threadIdx.x, lane = tid & 63, wid = tid >> 6;
  for (int i = tid; i < Dd * Dd; i += 256) ws[i] = W[i];
  __syncthreads();
  int nw = gridDim.x * 4;
  for (int row = blockIdx.x * 4 + wid; row < Nn; row += nw) {
    rb[wid * Dd + lane] = h[(size_t)row * Dd + lane];
    float acc = 0.f;
    #pragma unroll 16
    for (int k = 0; k < Dd; ++k) acc = fmaf(rb[wid * Dd + k], ws[k * Dd + lane], acc);
    m[(size_t)row * Dd + lane] = acc;
  }
}

__global__ __launch_bounds__(256) void k_agg(const float* __restrict__ m,
    const int* __restrict__ rowptr, const int* __restrict__ col, const float* __restrict__ en,
    const float* __restrict__ bb, float* __restrict__ agg,
    float* __restrict__ pS, float* __restrict__ pQ) {
  __shared__ float sS[256], sQ[256];
  int tid = threadIdx.x, lane = tid & 63, wid = tid >> 6;
  float bv = bb[lane];
  float ls = 0.f, lq = 0.f;
  int nw = gridDim.x * 4;
  for (int row = blockIdx.x * 4 + wid; row < Nn; row += nw) {
    int s0 = rowptr[row], s1 = rowptr[row + 1];
    float acc = bv;
    int e = s0;
    for (; e + 1 < s1; e += 2) {
      int c0 = col[e], c1 = col[e + 1];
      float w0 = en[e], w1 = en[e + 1];
      acc += w0 * m[(size_t)c0 * Dd + lane] + w1 * m[(size_t)c1 * Dd + lane];
    }
    if (e < s1) acc += en[e] * m[(size_t)col[e] * Dd + lane];
    agg[(size_t)row * Dd + lane] = acc;
    ls += acc; lq += acc * acc;
  }
  sS[tid] = ls; sQ[tid] = lq;
  __syncthreads();
  if (wid == 0) {
    float a = sS[lane] + sS[64 + lane] + sS[128 + lane] + sS[192 + lane];
    float q = sQ[lane] + sQ[64 + lane] + sQ[128 + lane] + sQ[192 + lane];
    pS[blockIdx.x * Dd + lane] = a;
    pQ[blockIdx.x * Dd + lane] = q;
  }
}

// h = relu(bn(agg)); s = learner(h - fused); h *= s; fused += h
__global__ __launch_bounds__(256) void k_post(const float* __restrict__ agg,
    const float* __restrict__ scaleA, const float* __restrict__ shiftA,
    const float* __restrict__ lw1p, const float* __restrict__ lb1p,
    const float* __restrict__ lw2p, const float* __restrict__ lb2p,
    float* __restrict__ h, float* __restrict__ fused) {
  int tid = threadIdx.x, lane = tid & 63, wid = tid >> 6;
  float4 w1 = reinterpret_cast<const float4*>(lw1p)[lane];
  float4 lb1v = *reinterpret_cast<const float4*>(lb1p);
  float4 l2 = *reinterpret_cast<const float4*>(lw2p);
  float lb2v = lb2p[0];
  float sc = scaleA[lane], sh = shiftA[lane];
  int nw = gridDim.x * 4;
  for (int row = blockIdx.x * 4 + wid; row < Nn; row += nw) {
    float a = agg[(size_t)row * Dd + lane];
    float hb = fmaxf(fmaf(a, sc, sh), 0.f);
    float fv = fused[(size_t)row * Dd + lane];
    float sgm = learner_sig(hb - fv, w1, lb1v, l2, lb2v);
    float hn = hb * sgm;
    h[(size_t)row * Dd + lane] = hn;
    fused[(size_t)row * Dd + lane] = fv + hn;
  }
}

// ---------------- output map ----------------

__global__ __launch_bounds__(256) void k_out1(const float* __restrict__ fused,
    const float* __restrict__ W, const float* __restrict__ b, float* __restrict__ z) {
  __shared__ float ws[Dd * FIN];
  __shared__ float rb[4 * Dd];
  int tid = threadIdx.x, lane = tid & 63, wid = tid >> 6;
  for (int i = tid; i < Dd * FIN; i += 256) ws[i] = W[i];
  __syncthreads();
  float b0 = b[lane], b1v = b[64 + lane];
  int nw = gridDim.x * 4;
  for (int row = blockIdx.x * 4 + wid; row < Nn; row += nw) {
    rb[wid * Dd + lane] = fused[(size_t)row * Dd + lane];
    float a0 = b0, a1 = b1v;
    #pragma unroll 16
    for (int k = 0; k < Dd; ++k) {
      float fv = rb[wid * Dd + k];
      a0 = fmaf(fv, ws[k * FIN + lane], a0);
      a1 = fmaf(fv, ws[k * FIN + 64 + lane], a1);
    }
    z[(size_t)row * FIN + lane] = fmaxf(a0, 0.f);
    z[(size_t)row * FIN + 64 + lane] = fmaxf(a1, 0.f);
  }
}

__global__ __launch_bounds__(256) void k_out2(const float* __restrict__ z,
    const float* __restrict__ W, const float* __restrict__ b, float* __restrict__ out) {
  __shared__ float ws[FIN * Dd];
  __shared__ float rb[4 * FIN];
  int tid = threadIdx.x, lane = tid & 63, wid = tid >> 6;
  for (int i = tid; i < FIN * Dd; i += 256) ws[i] = W[i];
  __syncthreads();
  float bv = b[lane];
  int nw = gridDim.x * 4;
  for (int row = blockIdx.x * 4 + wid; row < Nn; row += nw) {
    rb[wid * FIN + lane] = z[(size_t)row * FIN + lane];
    rb[wid * FIN + 64 + lane] = z[(size_t)row * FIN + 64 + lane];
    float acc = bv;
    #pragma unroll 16
    for (int k = 0; k < FIN; ++k) acc = fmaf(rb[wid * FIN + k], ws[k * Dd + lane], acc);
    out[(size_t)row * Dd + lane] = acc;
  }
}

// ---------------- launch ----------------

extern "C" void kernel_launch(void* const* d_in, const int* in_sizes, int n_in,
                              void* d_out, int out_size, void* d_ws, size_t ws_size,
                              hipStream_t stream) {
  const float* x      = (const float*)d_in[0];
  const int*   ei     = (const int*)d_in[1];
  const float* im_w1  = (const float*)d_in[2];
  const float* im_b1  = (const float*)d_in[3];
  const float* im_g1  = (const float*)d_in[4];
  const float* im_be1 = (const float*)d_in[5];
  const float* im_w2  = (const float*)d_in[6];
  const float* im_b2  = (const float*)d_in[7];
  const float* lw1    = (const float*)d_in[8];
  const float* lb1    = (const float*)d_in[9];
  const float* lw2    = (const float*)d_in[10];
  const float* lb2    = (const float*)d_in[11];
  const float* bw     = (const float*)d_in[12];
  const float* bb     = (const float*)d_in[13];
  const float* bg     = (const float*)d_in[14];
  const float* bbe    = (const float*)d_in[15];
  const float* om_w1  = (const float*)d_in[16];
  const float* om_b1  = (const float*)d_in[17];
  const float* om_w2  = (const float*)d_in[18];
  const float* om_b2  = (const float*)d_in[19];
  float* out = (float*)d_out;

  char* w = (char*)d_ws;
  size_t off = 0;
  auto alloc = [&](size_t bytes) -> void* {
    void* p = w + off;
    off = (off + bytes + 255) & ~(size_t)255;
    return p;
  };
  int*   deg    = (int*)alloc((size_t)Nn * 4);
  int*   fill   = (int*)alloc((size_t)Nn * 4);
  size_t zero_bytes = off;
  int*   rowptr = (int*)alloc((size_t)(Nn + 1) * 4);
  int*   col    = (int*)alloc((size_t)ETe * 4);
  float* en     = (float*)alloc((size_t)ETe * 4);
  float* dinv   = (float*)alloc((size_t)Nn * 4);
  float* pS     = (float*)alloc((size_t)1563 * 128 * 4);
  float* pQ     = (float*)alloc((size_t)1563 * 128 * 4);
  float* scaleA = (float*)alloc(128 * 4);
  float* shiftA = (float*)alloc(128 * 4);
  float* tb     = (float*)alloc((size_t)Nn * FIN * 4);
  float* h      = (float*)alloc((size_t)Nn * Dd * 4);
  float* fused  = (float*)alloc((size_t)Nn * Dd * 4);
  float* m   = tb;                    // reuse of tb region
  float* agg = tb + (size_t)Nn * Dd;  // second half of tb
  float* z   = tb;                    // reuse again for output map
  (void)fill; (void)deg;

  hipMemsetAsync(d_ws, 0, zero_bytes, stream);
  k_deg<<<(ETe + 255) / 256, 256, 0, stream>>>(ei, deg);
  k_scan<<<1, 1024, 0, stream>>>(deg, rowptr);
  k_dinv<<<(Nn + 255) / 256, 256, 0, stream>>>(rowptr, dinv);
  k_fill<<<(ETe + 255) / 256, 256, 0, stream>>>(ei, rowptr, fill, dinv, col, en);

  k_ingemm<<<1563, 256, 0, stream>>>(x, im_w1, im_b1, tb, pS, pQ);
  k_finalize<<<1, 1024, 0, stream>>>(pS, pQ, 1563, 128, im_g1, im_be1, scaleA, shiftA);
  k_inmap2<<<512, 256, 0, stream>>>(tb, im_w2, im_b2, scaleA, shiftA, lw1, lb1, lw2, lb2, h, fused);

  for (int i = 0; i < LL; ++i) {
    k_gemm64<<<512, 256, 0, stream>>>(h, bw + (size_t)i * Dd * Dd, m);
    k_agg<<<512, 256, 0, stream>>>(m, rowptr, col, en, bb + i * Dd, agg, pS, pQ);
    k_finalize<<<1, 1024, 0, stream>>>(pS, pQ, 512, 64, bg + i * Dd, bbe + i * Dd, scaleA, shiftA);
    k_post<<<512, 256, 0, stream>>>(agg, scaleA, shiftA, lw1 + (size_t)(i + 1) * 256,
                                    lb1 + (size_t)(i + 1) * 4, lw2 + (size_t)(i + 1) * 4,
                                    lb2 + (i + 1), h, fused);
  }

  k_out1<<<512, 256, 0, stream>>>(fused, om_w1, om_b1, z);
  k_out2<<<512, 256, 0, stream>>>(z, om_w2, om_b2, out);
}

// Round 2
// 1345.251 us; speedup vs baseline: 1.5037x; 1.5037x over previous
//
#include <hip/hip_runtime.h>
#include <hip/hip_fp16.h>
#include <math.h>

#define Nn 50000
#define Ee 800000
#define ETe 850000   // E + N self loops
#define Dd 64
#define FIN 128
#define LL 8

// ---------------- graph build ----------------

__global__ __launch_bounds__(256) void k_deg(const int* __restrict__ ei, int* __restrict__ deg) {
  int e = blockIdx.x * 256 + threadIdx.x;
  if (e >= ETe) return;
  int dst = (e < Ee) ? ei[Ee + e] : (e - Ee);
  atomicAdd(&deg[dst], 1);
}

__global__ __launch_bounds__(1024) void k_scan(const int* __restrict__ deg, int* __restrict__ rowptr) {
  __shared__ int wsum[16];
  int tid = threadIdx.x;
  int lane = tid & 63, wid = tid >> 6;
  int carry = 0;
  for (int base = 0; base < Nn; base += 1024) {
    int i = base + tid;
    int v = (i < Nn) ? deg[i] : 0;
    int s = v;
    #pragma unroll
    for (int off = 1; off < 64; off <<= 1) {
      int t = __shfl_up(s, off, 64);
      if (lane >= off) s += t;
    }
    if (lane == 63) wsum[wid] = s;
    __syncthreads();
    if (wid == 0) {
      int ws = (lane < 16) ? wsum[lane] : 0;
      #pragma unroll
      for (int off = 1; off < 16; off <<= 1) {
        int t = __shfl_up(ws, off, 64);
        if (lane >= off) ws += t;
      }
      if (lane < 16) wsum[lane] = ws;
    }
    __syncthreads();
    int wexcl = (wid == 0) ? 0 : wsum[wid - 1];
    if (i < Nn) rowptr[i + 1] = carry + wexcl + s;
    carry += wsum[15];
    __syncthreads();
  }
  if (tid == 0) rowptr[0] = 0;
}

__global__ __launch_bounds__(256) void k_dinv(const int* __restrict__ rowptr, float* __restrict__ dinv) {
  int n = blockIdx.x * 256 + threadIdx.x;
  if (n >= Nn) return;
  int d = rowptr[n + 1] - rowptr[n];   // >= 1 (self loop)
  dinv[n] = rsqrtf((float)d);
}

__global__ __launch_bounds__(256) void k_fill(const int* __restrict__ ei, const int* __restrict__ rowptr,
                                              int* __restrict__ fill, const float* __restrict__ dinv,
                                              int2* __restrict__ ce) {
  int e = blockIdx.x * 256 + threadIdx.x;
  if (e >= ETe) return;
  int src, dst;
  if (e < Ee) { src = ei[e]; dst = ei[Ee + e]; }
  else { src = e - Ee; dst = src; }
  int pos = rowptr[dst] + atomicAdd(&fill[dst], 1);
  float w = dinv[src] * dinv[dst];
  ce[pos] = make_int2(src, __float_as_int(w));
}

// ---------------- learner MLP (per-wave, 64 lanes = 64 channels) ----------------

__device__ __forceinline__ float learner_sig(float hm, const float4 w1, const float4 lb1v,
                                             const float4 l2, float lb2v) {
  float p0 = hm * w1.x, p1 = hm * w1.y, p2 = hm * w1.z, p3 = hm * w1.w;
  #pragma unroll
  for (int off = 32; off > 0; off >>= 1) {
    p0 += __shfl_xor(p0, off, 64);
    p1 += __shfl_xor(p1, off, 64);
    p2 += __shfl_xor(p2, off, 64);
    p3 += __shfl_xor(p3, off, 64);
  }
  float z0 = p0 + lb1v.x; z0 = z0 > 0.f ? z0 : 0.2f * z0;
  float z1 = p1 + lb1v.y; z1 = z1 > 0.f ? z1 : 0.2f * z1;
  float z2 = p2 + lb1v.z; z2 = z2 > 0.f ? z2 : 0.2f * z2;
  float z3 = p3 + lb1v.w; z3 = z3 > 0.f ? z3 : 0.2f * z3;
  float lg = z0 * l2.x + z1 * l2.y + z2 * l2.z + z3 * l2.w + lb2v;
  return 1.f / (1.f + expf(-lg));
}

// ---------------- input map ----------------

// t = x @ W1 + b1 (fp16 out), BN stats via block-reduce + atomicAdd
__global__ __launch_bounds__(256) void k_ingemm(const float* __restrict__ x,
    const float* __restrict__ W1, const float* __restrict__ b1,
    __half* __restrict__ t, float* __restrict__ statS, float* __restrict__ statQ) {
  __shared__ float xs[32 * FIN];
  __shared__ float ws[64 * FIN];
  int tid = threadIdx.x;
  int row0 = blockIdx.x * 32;
  for (int i = tid; i < 32 * FIN; i += 256) {
    int r = i >> 7, c = i & 127;
    int gr = row0 + r;
    xs[i] = (gr < Nn) ? x[(size_t)gr * FIN + c] : 0.f;
  }
  int colc = tid & 127;
  int rp = tid >> 7;   // 0..1
  float acc[16];
  #pragma unroll
  for (int i = 0; i < 16; ++i) acc[i] = 0.f;
  for (int kc = 0; kc < 2; ++kc) {
    __syncthreads();
    for (int i = tid; i < 64 * FIN; i += 256) ws[i] = W1[kc * 64 * FIN + i];
    __syncthreads();
    for (int k = 0; k < 64; ++k) {
      float wv = ws[k * FIN + colc];
      #pragma unroll
      for (int rr = 0; rr < 16; ++rr)
        acc[rr] = fmaf(xs[(rr * 2 + rp) * FIN + kc * 64 + k], wv, acc[rr]);
    }
  }
  float bv = b1[colc];
  float s = 0.f, q = 0.f;
  #pragma unroll
  for (int rr = 0; rr < 16; ++rr) {
    int gr = row0 + rr * 2 + rp;
    if (gr < Nn) {
      float v = acc[rr] + bv;
      t[(size_t)gr * FIN + colc] = __float2half(v);
      s += v; q += v * v;
    }
  }
  __syncthreads();
  xs[tid] = s; xs[256 + tid] = q;
  __syncthreads();
  if (rp == 0) {
    float st = xs[colc] + xs[128 + colc];
    float qt = xs[256 + colc] + xs[384 + colc];
    atomicAdd(&statS[colc], st);
    atomicAdd(&statQ[colc], qt);
  }
}

// h0 = relu(bn(t)) @ W2 + b2 ; learner0 ; fused = h0 ; m0 = h0 @ bw0 (fp16)
__global__ __launch_bounds__(256) void k_inmap2(
    const __half* __restrict__ t, const float* __restrict__ W2, const float* __restrict__ b2,
    const float* __restrict__ statS, const float* __restrict__ statQ,
    const float* __restrict__ g1, const float* __restrict__ be1,
    const float* __restrict__ lw1p, const float* __restrict__ lb1p,
    const float* __restrict__ lw2p, const float* __restrict__ lb2p,
    const float* __restrict__ W0, float* __restrict__ fused, __half* __restrict__ m0) {
  __shared__ float ws[FIN * Dd];
  __shared__ float w0s[Dd * Dd];
  __shared__ float rb[4 * FIN];
  __shared__ float rh[4 * Dd];
  __shared__ float scs[FIN], shs[FIN];
  int tid = threadIdx.x, lane = tid & 63, wid = tid >> 6;
  for (int i = tid; i < FIN * Dd; i += 256) ws[i] = W2[i];
  for (int i = tid; i < Dd * Dd; i += 256) w0s[i] = W0[i];
  if (tid < FIN) {
    float mu = statS[tid] * (1.f / Nn);
    float var = statQ[tid] * (1.f / Nn) - mu * mu;
    float rs = rsqrtf(var + 1e-5f);
    float scv = g1[tid] * rs;
    scs[tid] = scv; shs[tid] = be1[tid] - mu * scv;
  }
  __syncthreads();
  float4 w1 = reinterpret_cast<const float4*>(lw1p)[lane];
  float4 lb1v = *reinterpret_cast<const float4*>(lb1p);
  float4 l2 = *reinterpret_cast<const float4*>(lw2p);
  float lb2v = lb2p[0];
  float sc0 = scs[lane], sh0 = shs[lane];
  float sc1 = scs[64 + lane], sh1 = shs[64 + lane];
  float bv = b2[lane];
  int nw = gridDim.x * 4;
  for (int row = blockIdx.x * 4 + wid; row < Nn; row += nw) {
    float v0 = __half2float(t[(size_t)row * FIN + lane]);
    float v1 = __half2float(t[(size_t)row * FIN + 64 + lane]);
    v0 = fmaxf(fmaf(v0, sc0, sh0), 0.f);
    v1 = fmaxf(fmaf(v1, sc1, sh1), 0.f);
    rb[wid * FIN + lane] = v0;
    rb[wid * FIN + 64 + lane] = v1;
    float acc = bv;
    #pragma unroll 16
    for (int k = 0; k < FIN; ++k) acc = fmaf(rb[wid * FIN + k], ws[k * Dd + lane], acc);
    float sgm = learner_sig(acc, w1, lb1v, l2, lb2v);
    float hn = acc * sgm;
    fused[(size_t)row * Dd + lane] = hn;
    rh[wid * Dd + lane] = hn;
    float am = 0.f;
    #pragma unroll 16
    for (int k = 0; k < Dd; ++k) am = fmaf(rh[wid * Dd + k], w0s[k * Dd + lane], am);
    m0[(size_t)row * Dd + lane] = __float2half(am);
  }
}

// ---------------- per-layer kernels ----------------

// agg = segsum(m[src]*w) + bb ; BN stats
__global__ __launch_bounds__(256) void k_agg(const __half* __restrict__ m,
    const int* __restrict__ rowptr, const int2* __restrict__ ce,
    const float* __restrict__ bb, float* __restrict__ agg,
    float* __restrict__ statS, float* __restrict__ statQ) {
  __shared__ float sS[256], sQ[256];
  int tid = threadIdx.x, lane = tid & 63, wid = tid >> 6;
  float bv = bb[lane];
  float ls = 0.f, lq = 0.f;
  int nw = gridDim.x * 4;
  for (int row = blockIdx.x * 4 + wid; row < Nn; row += nw) {
    int s0 = rowptr[row], s1 = rowptr[row + 1];
    float acc = bv;
    for (int base = s0; base < s1; base += 64) {
      int2 cw = make_int2(0, 0);
      if (base + lane < s1) cw = ce[base + lane];
      int n = min(64, s1 - base);
      #pragma unroll 4
      for (int j = 0; j < n; ++j) {
        int cj = __shfl(cw.x, j, 64);
        float wj = __int_as_float(__shfl(cw.y, j, 64));
        acc = fmaf(wj, __half2float(m[(unsigned)cj * Dd + lane]), acc);
      }
    }
    agg[(size_t)row * Dd + lane] = acc;
    ls += acc; lq += acc * acc;
  }
  sS[tid] = ls; sQ[tid] = lq;
  __syncthreads();
  if (tid < 64) {
    float a = sS[tid] + sS[64 + tid] + sS[128 + tid] + sS[192 + tid];
    float q = sQ[tid] + sQ[64 + tid] + sQ[128 + tid] + sQ[192 + tid];
    atomicAdd(&statS[tid], a);
    atomicAdd(&statQ[tid], q);
  }
}

// h = relu(bn(agg)); s = learner(h - fused); hn = h*s; fused += hn; mnext = hn @ W (fp16)
__global__ __launch_bounds__(256) void k_post(const float* __restrict__ agg,
    const float* __restrict__ statS, const float* __restrict__ statQ,
    const float* __restrict__ gamma, const float* __restrict__ beta,
    const float* __restrict__ lw1p, const float* __restrict__ lb1p,
    const float* __restrict__ lw2p, const float* __restrict__ lb2p,
    const float* __restrict__ W, float* __restrict__ fused, __half* __restrict__ mnext,
    int do_gemm) {
  __shared__ float ws[Dd * Dd];
  __shared__ float rh[4 * Dd];
  __shared__ float scs[Dd], shs[Dd];
  int tid = threadIdx.x, lane = tid & 63, wid = tid >> 6;
  if (do_gemm) for (int i = tid; i < Dd * Dd; i += 256) ws[i] = W[i];
  if (tid < Dd) {
    float mu = statS[tid] * (1.f / Nn);
    float var = statQ[tid] * (1.f / Nn) - mu * mu;
    float rs = rsqrtf(var + 1e-5f);
    float scv = gamma[tid] * rs;
    scs[tid] = scv; shs[tid] = beta[tid] - mu * scv;
  }
  __syncthreads();
  float4 w1 = reinterpret_cast<const float4*>(lw1p)[lane];
  float4 lb1v = *reinterpret_cast<const float4*>(lb1p);
  float4 l2 = *reinterpret_cast<const float4*>(lw2p);
  float lb2v = lb2p[0];
  float sc = scs[lane], sh = shs[lane];
  int nw = gridDim.x * 4;
  for (int row = blockIdx.x * 4 + wid; row < Nn; row += nw) {
    float a = agg[(size_t)row * Dd + lane];
    float hb = fmaxf(fmaf(a, sc, sh), 0.f);
    float fv = fused[(size_t)row * Dd + lane];
    float sgm = learner_sig(hb - fv, w1, lb1v, l2, lb2v);
    float hn = hb * sgm;
    fused[(size_t)row * Dd + lane] = fv + hn;
    if (do_gemm) {
      rh[wid * Dd + lane] = hn;
      float am = 0.f;
      #pragma unroll 16
      for (int k = 0; k < Dd; ++k) am = fmaf(rh[wid * Dd + k], ws[k * Dd + lane], am);
      mnext[(size_t)row * Dd + lane] = __float2half(am);
    }
  }
}

// ---------------- output map (fused) ----------------

__global__ __launch_bounds__(256) void k_outmap(const float* __restrict__ fused,
    const float* __restrict__ W1, const float* __restrict__ b1,
    const float* __restrict__ W2, const float* __restrict__ b2, float* __restrict__ out) {
  __shared__ float ws1[Dd * FIN];
  __shared__ float ws2[FIN * Dd];
  __shared__ float rf[4 * Dd];
  __shared__ float rz[4 * FIN];
  int tid = threadIdx.x, lane = tid & 63, wid = tid >> 6;
  for (int i = tid; i < Dd * FIN; i += 256) { ws1[i] = W1[i]; ws2[i] = W2[i]; }
  __syncthreads();
  float b10 = b1[lane], b11 = b1[64 + lane], b2v = b2[lane];
  int nw = gridDim.x * 4;
  for (int row = blockIdx.x * 4 + wid; row < Nn; row += nw) {
    rf[wid * Dd + lane] = fused[(size_t)row * Dd + lane];
    float a0 = b10, a1 = b11;
    #pragma unroll 16
    for (int k = 0; k < Dd; ++k) {
      float fv = rf[wid * Dd + k];
      a0 = fmaf(fv, ws1[k * FIN + lane], a0);
      a1 = fmaf(fv, ws1[k * FIN + 64 + lane], a1);
    }
    rz[wid * FIN + lane] = fmaxf(a0, 0.f);
    rz[wid * FIN + 64 + lane] = fmaxf(a1, 0.f);
    float acc = b2v;
    #pragma unroll 16
    for (int k = 0; k < FIN; ++k) acc = fmaf(rz[wid * FIN + k], ws2[k * Dd + lane], acc);
    out[(size_t)row * Dd + lane] = acc;
  }
}

// ---------------- launch ----------------

extern "C" void kernel_launch(void* const* d_in, const int* in_sizes, int n_in,
                              void* d_out, int out_size, void* d_ws, size_t ws_size,
                              hipStream_t stream) {
  const float* x      = (const float*)d_in[0];
  const int*   ei     = (const int*)d_in[1];
  const float* im_w1  = (const float*)d_in[2];
  const float* im_b1  = (const float*)d_in[3];
  const float* im_g1  = (const float*)d_in[4];
  const float* im_be1 = (const float*)d_in[5];
  const float* im_w2  = (const float*)d_in[6];
  const float* im_b2  = (const float*)d_in[7];
  const float* lw1    = (const float*)d_in[8];
  const float* lb1    = (const float*)d_in[9];
  const float* lw2    = (const float*)d_in[10];
  const float* lb2    = (const float*)d_in[11];
  const float* bw     = (const float*)d_in[12];
  const float* bb     = (const float*)d_in[13];
  const float* bg     = (const float*)d_in[14];
  const float* bbe    = (const float*)d_in[15];
  const float* om_w1  = (const float*)d_in[16];
  const float* om_b1  = (const float*)d_in[17];
  const float* om_w2  = (const float*)d_in[18];
  const float* om_b2  = (const float*)d_in[19];
  float* out = (float*)d_out;

  char* w = (char*)d_ws;
  size_t off = 0;
  auto alloc = [&](size_t bytes) -> void* {
    void* p = w + off;
    off = (off + bytes + 255) & ~(size_t)255;
    return p;
  };
  // zeroed region first
  int*   deg    = (int*)alloc((size_t)Nn * 4);
  int*   fill   = (int*)alloc((size_t)Nn * 4);
  float* statS  = (float*)alloc((size_t)9 * 128 * 4);
  float* statQ  = (float*)alloc((size_t)9 * 128 * 4);
  size_t zero_bytes = off;
  int*   rowptr = (int*)alloc((size_t)(Nn + 1) * 4);
  int2*  ce     = (int2*)alloc((size_t)ETe * 8);
  float* dinv   = (float*)alloc((size_t)Nn * 4);
  __half* t     = (__half*)alloc((size_t)Nn * FIN * 2);
  __half* m     = (__half*)alloc((size_t)Nn * Dd * 2);
  float* agg    = (float*)alloc((size_t)Nn * Dd * 4);
  float* fused  = (float*)alloc((size_t)Nn * Dd * 4);
  (void)deg; (void)fill;

  hipMemsetAsync(d_ws, 0, zero_bytes, stream);
  k_deg<<<(ETe + 255) / 256, 256, 0, stream>>>(ei, deg);
  k_scan<<<1, 1024, 0, stream>>>(deg, rowptr);
  k_dinv<<<(Nn + 255) / 256, 256, 0, stream>>>(rowptr, dinv);
  k_fill<<<(ETe + 255) / 256, 256, 0, stream>>>(ei, rowptr, fill, dinv, ce);

  k_ingemm<<<1563, 256, 0, stream>>>(x, im_w1, im_b1, t, statS, statQ);
  k_inmap2<<<1024, 256, 0, stream>>>(t, im_w2, im_b2, statS, statQ, im_g1, im_be1,
                                     lw1, lb1, lw2, lb2, bw, fused, m);

  for (int i = 0; i < LL; ++i) {
    float* sS = statS + (size_t)(1 + i) * 128;
    float* sQ = statQ + (size_t)(1 + i) * 128;
    k_agg<<<2048, 256, 0, stream>>>(m, rowptr, ce, bb + i * Dd, agg, sS, sQ);
    k_post<<<1024, 256, 0, stream>>>(agg, sS, sQ, bg + i * Dd, bbe + i * Dd,
                                     lw1 + (size_t)(i + 1) * 256, lb1 + (size_t)(i + 1) * 4,
                                     lw2 + (size_t)(i + 1) * 4, lb2 + (i + 1),
                                     (i + 1 < LL) ? bw + (size_t)(i + 1) * Dd * Dd : bw,
                                     fused, m, (i + 1 < LL) ? 1 : 0);
  }

  k_outmap<<<1024, 256, 0, stream>>>(fused, om_w1, om_b1, om_w2, om_b2, out);
}

// Round 3
// 1087.062 us; speedup vs baseline: 1.8608x; 1.2375x over previous
//
#include <hip/hip_runtime.h>
#include <hip/hip_fp16.h>
#include <math.h>

#define Nn 50000
#define Ee 800000
#define ETe 850000   // E + N self loops
#define Dd 64
#define FIN 128
#define LL 8

// ---------------- graph build ----------------

__global__ __launch_bounds__(256) void k_deg(const int* __restrict__ ei, int* __restrict__ deg) {
  int e = blockIdx.x * 256 + threadIdx.x;
  if (e >= ETe) return;
  int dst = (e < Ee) ? ei[Ee + e] : (e - Ee);
  atomicAdd(&deg[dst], 1);
}

__global__ __launch_bounds__(1024) void k_scan(const int* __restrict__ deg, int* __restrict__ rowptr) {
  __shared__ int wsum[16];
  int tid = threadIdx.x;
  int lane = tid & 63, wid = tid >> 6;
  int carry = 0;
  for (int base = 0; base < Nn; base += 1024) {
    int i = base + tid;
    int v = (i < Nn) ? deg[i] : 0;
    int s = v;
    #pragma unroll
    for (int off = 1; off < 64; off <<= 1) {
      int t = __shfl_up(s, off, 64);
      if (lane >= off) s += t;
    }
    if (lane == 63) wsum[wid] = s;
    __syncthreads();
    if (wid == 0) {
      int ws = (lane < 16) ? wsum[lane] : 0;
      #pragma unroll
      for (int off = 1; off < 16; off <<= 1) {
        int t = __shfl_up(ws, off, 64);
        if (lane >= off) ws += t;
      }
      if (lane < 16) wsum[lane] = ws;
    }
    __syncthreads();
    int wexcl = (wid == 0) ? 0 : wsum[wid - 1];
    if (i < Nn) rowptr[i + 1] = carry + wexcl + s;
    carry += wsum[15];
    __syncthreads();
  }
  if (tid == 0) rowptr[0] = 0;
}

__global__ __launch_bounds__(256) void k_dinv(const int* __restrict__ rowptr, float* __restrict__ dinv) {
  int n = blockIdx.x * 256 + threadIdx.x;
  if (n >= Nn) return;
  int d = rowptr[n + 1] - rowptr[n];   // >= 1 (self loop)
  dinv[n] = rsqrtf((float)d);
}

__global__ __launch_bounds__(256) void k_fill(const int* __restrict__ ei, const int* __restrict__ rowptr,
                                              int* __restrict__ fill, const float* __restrict__ dinv,
                                              int2* __restrict__ ce) {
  int e = blockIdx.x * 256 + threadIdx.x;
  if (e >= ETe) return;
  int src, dst;
  if (e < Ee) { src = ei[e]; dst = ei[Ee + e]; }
  else { src = e - Ee; dst = src; }
  int pos = rowptr[dst] + atomicAdd(&fill[dst], 1);
  float w = dinv[src] * dinv[dst];
  ce[pos] = make_int2(src, __float_as_int(w));
}

// ---------------- learner MLP (per-wave, 64 lanes = 64 channels) ----------------

__device__ __forceinline__ float learner_sig(float hm, const float4 w1, const float4 lb1v,
                                             const float4 l2, float lb2v) {
  float p0 = hm * w1.x, p1 = hm * w1.y, p2 = hm * w1.z, p3 = hm * w1.w;
  #pragma unroll
  for (int off = 32; off > 0; off >>= 1) {
    p0 += __shfl_xor(p0, off, 64);
    p1 += __shfl_xor(p1, off, 64);
    p2 += __shfl_xor(p2, off, 64);
    p3 += __shfl_xor(p3, off, 64);
  }
  float z0 = p0 + lb1v.x; z0 = z0 > 0.f ? z0 : 0.2f * z0;
  float z1 = p1 + lb1v.y; z1 = z1 > 0.f ? z1 : 0.2f * z1;
  float z2 = p2 + lb1v.z; z2 = z2 > 0.f ? z2 : 0.2f * z2;
  float z3 = p3 + lb1v.w; z3 = z3 > 0.f ? z3 : 0.2f * z3;
  float lg = z0 * l2.x + z1 * l2.y + z2 * l2.z + z3 * l2.w + lb2v;
  return 1.f / (1.f + expf(-lg));
}

// ---------------- input map ----------------

// t = x @ W1 + b1 (fp16 out), BN stats via block-reduce + atomicAdd
__global__ __launch_bounds__(256) void k_ingemm(const float* __restrict__ x,
    const float* __restrict__ W1, const float* __restrict__ b1,
    __half* __restrict__ t, float* __restrict__ statS, float* __restrict__ statQ) {
  __shared__ float xs[32 * FIN];
  __shared__ float ws[64 * FIN];
  int tid = threadIdx.x;
  int row0 = blockIdx.x * 32;
  for (int i = tid; i < 32 * FIN; i += 256) {
    int r = i >> 7, c = i & 127;
    int gr = row0 + r;
    xs[i] = (gr < Nn) ? x[(size_t)gr * FIN + c] : 0.f;
  }
  int colc = tid & 127;
  int rp = tid >> 7;   // 0..1
  float acc[16];
  #pragma unroll
  for (int i = 0; i < 16; ++i) acc[i] = 0.f;
  for (int kc = 0; kc < 2; ++kc) {
    __syncthreads();
    for (int i = tid; i < 64 * FIN; i += 256) ws[i] = W1[kc * 64 * FIN + i];
    __syncthreads();
    for (int k = 0; k < 64; ++k) {
      float wv = ws[k * FIN + colc];
      #pragma unroll
      for (int rr = 0; rr < 16; ++rr)
        acc[rr] = fmaf(xs[(rr * 2 + rp) * FIN + kc * 64 + k], wv, acc[rr]);
    }
  }
  float bv = b1[colc];
  float s = 0.f, q = 0.f;
  #pragma unroll
  for (int rr = 0; rr < 16; ++rr) {
    int gr = row0 + rr * 2 + rp;
    if (gr < Nn) {
      float v = acc[rr] + bv;
      t[(size_t)gr * FIN + colc] = __float2half(v);
      s += v; q += v * v;
    }
  }
  __syncthreads();
  xs[tid] = s; xs[256 + tid] = q;
  __syncthreads();
  if (rp == 0) {
    float st = xs[colc] + xs[128 + colc];
    float qt = xs[256 + colc] + xs[384 + colc];
    atomicAdd(&statS[colc], st);
    atomicAdd(&statQ[colc], qt);
  }
}

// h0 = relu(bn(t)) @ W2 + b2 ; learner0 ; fused = h0 ; h16 = fp16(h0)
__global__ __launch_bounds__(256) void k_inmap2(
    const __half* __restrict__ t, const float* __restrict__ W2, const float* __restrict__ b2,
    const float* __restrict__ statS, const float* __restrict__ statQ,
    const float* __restrict__ g1, const float* __restrict__ be1,
    const float* __restrict__ lw1p, const float* __restrict__ lb1p,
    const float* __restrict__ lw2p, const float* __restrict__ lb2p,
    float* __restrict__ fused, __half* __restrict__ h16) {
  __shared__ float ws[FIN * Dd];
  __shared__ float rb[4 * FIN];
  __shared__ float scs[FIN], shs[FIN];
  int tid = threadIdx.x, lane = tid & 63, wid = tid >> 6;
  for (int i = tid; i < FIN * Dd; i += 256) ws[i] = W2[i];
  if (tid < FIN) {
    float mu = statS[tid] * (1.f / Nn);
    float var = statQ[tid] * (1.f / Nn) - mu * mu;
    float rs = rsqrtf(var + 1e-5f);
    float scv = g1[tid] * rs;
    scs[tid] = scv; shs[tid] = be1[tid] - mu * scv;
  }
  __syncthreads();
  float4 w1 = reinterpret_cast<const float4*>(lw1p)[lane];
  float4 lb1v = *reinterpret_cast<const float4*>(lb1p);
  float4 l2 = *reinterpret_cast<const float4*>(lw2p);
  float lb2v = lb2p[0];
  float sc0 = scs[lane], sh0 = shs[lane];
  float sc1 = scs[64 + lane], sh1 = shs[64 + lane];
  float bv = b2[lane];
  int nw = gridDim.x * 4;
  for (int row = blockIdx.x * 4 + wid; row < Nn; row += nw) {
    float v0 = __half2float(t[(size_t)row * FIN + lane]);
    float v1 = __half2float(t[(size_t)row * FIN + 64 + lane]);
    v0 = fmaxf(fmaf(v0, sc0, sh0), 0.f);
    v1 = fmaxf(fmaf(v1, sc1, sh1), 0.f);
    rb[wid * FIN + lane] = v0;
    rb[wid * FIN + 64 + lane] = v1;
    float acc = bv;
    #pragma unroll 16
    for (int k = 0; k < FIN; ++k) acc = fmaf(rb[wid * FIN + k], ws[k * Dd + lane], acc);
    float sgm = learner_sig(acc, w1, lb1v, l2, lb2v);
    float hn = acc * sgm;
    fused[(size_t)row * Dd + lane] = hn;
    h16[(size_t)row * Dd + lane] = __float2half(hn);
  }
}

// ---------------- per-layer kernels ----------------

// s = segsum(h16[src]*w) ; o = s @ W + bb ; agg16 = fp16(o) ; BN stats on o
__global__ __launch_bounds__(256) void k_agg(const __half* __restrict__ h16,
    const int* __restrict__ rowptr, const int2* __restrict__ ce,
    const float* __restrict__ bb, const float* __restrict__ W,
    __half* __restrict__ agg, float* __restrict__ statS, float* __restrict__ statQ) {
  __shared__ float ws[Dd * Dd];
  __shared__ float sA[4 * Dd];
  __shared__ float sS[256], sQ[256];
  int tid = threadIdx.x, lane = tid & 63, wid = tid >> 6;
  for (int i = tid; i < Dd * Dd; i += 256) ws[i] = W[i];
  __syncthreads();
  float bv = bb[lane];
  float ls = 0.f, lq = 0.f;
  int nw = gridDim.x * 4;
  for (int row = blockIdx.x * 4 + wid; row < Nn; row += nw) {
    int s0 = rowptr[row], s1 = rowptr[row + 1];
    float acc = 0.f;
    for (int base = s0; base < s1; base += 64) {
      int2 cw = make_int2(0, 0);
      if (base + lane < s1) cw = ce[base + lane];
      int n = min(64, s1 - base);
      int j = 0;
      for (; j + 4 <= n; j += 4) {
        // 4 independent gathers in flight; scalar bases via readfirstlane
        int c0 = __builtin_amdgcn_readfirstlane(__shfl(cw.x, j, 64));
        int c1 = __builtin_amdgcn_readfirstlane(__shfl(cw.x, j + 1, 64));
        int c2 = __builtin_amdgcn_readfirstlane(__shfl(cw.x, j + 2, 64));
        int c3 = __builtin_amdgcn_readfirstlane(__shfl(cw.x, j + 3, 64));
        float w0 = __int_as_float(__shfl(cw.y, j, 64));
        float w1 = __int_as_float(__shfl(cw.y, j + 1, 64));
        float w2 = __int_as_float(__shfl(cw.y, j + 2, 64));
        float w3 = __int_as_float(__shfl(cw.y, j + 3, 64));
        float v0 = __half2float(h16[(unsigned)c0 * Dd + lane]);
        float v1 = __half2float(h16[(unsigned)c1 * Dd + lane]);
        float v2 = __half2float(h16[(unsigned)c2 * Dd + lane]);
        float v3 = __half2float(h16[(unsigned)c3 * Dd + lane]);
        acc = fmaf(w0, v0, acc);
        acc = fmaf(w1, v1, acc);
        acc = fmaf(w2, v2, acc);
        acc = fmaf(w3, v3, acc);
      }
      for (; j < n; ++j) {
        int cj = __builtin_amdgcn_readfirstlane(__shfl(cw.x, j, 64));
        float wj = __int_as_float(__shfl(cw.y, j, 64));
        acc = fmaf(wj, __half2float(h16[(unsigned)cj * Dd + lane]), acc);
      }
    }
    // fused GEMM: o[lane] = sum_k acc[k] * W[k][lane] + bias
    sA[wid * Dd + lane] = acc;   // wave-private staging
    float o = bv;
    #pragma unroll 16
    for (int k = 0; k < Dd; ++k) o = fmaf(sA[wid * Dd + k], ws[k * Dd + lane], o);
    agg[(size_t)row * Dd + lane] = __float2half(o);
    ls += o; lq += o * o;
  }
  sS[tid] = ls; sQ[tid] = lq;
  __syncthreads();
  if (tid < 64) {
    float a = sS[tid] + sS[64 + tid] + sS[128 + tid] + sS[192 + tid];
    float q = sQ[tid] + sQ[64 + tid] + sQ[128 + tid] + sQ[192 + tid];
    atomicAdd(&statS[tid], a);
    atomicAdd(&statQ[tid], q);
  }
}

// h = relu(bn(agg)); s = learner(h - fused); hn = h*s; fused += hn; h16 = fp16(hn)
__global__ __launch_bounds__(256) void k_post(const __half* __restrict__ agg,
    const float* __restrict__ statS, const float* __restrict__ statQ,
    const float* __restrict__ gamma, const float* __restrict__ beta,
    const float* __restrict__ lw1p, const float* __restrict__ lb1p,
    const float* __restrict__ lw2p, const float* __restrict__ lb2p,
    float* __restrict__ fused, __half* __restrict__ h16, int do_h) {
  __shared__ float scs[Dd], shs[Dd];
  int tid = threadIdx.x, lane = tid & 63, wid = tid >> 6;
  if (tid < Dd) {
    float mu = statS[tid] * (1.f / Nn);
    float var = statQ[tid] * (1.f / Nn) - mu * mu;
    float rs = rsqrtf(var + 1e-5f);
    float scv = gamma[tid] * rs;
    scs[tid] = scv; shs[tid] = beta[tid] - mu * scv;
  }
  __syncthreads();
  float4 w1 = reinterpret_cast<const float4*>(lw1p)[lane];
  float4 lb1v = *reinterpret_cast<const float4*>(lb1p);
  float4 l2 = *reinterpret_cast<const float4*>(lw2p);
  float lb2v = lb2p[0];
  float sc = scs[lane], sh = shs[lane];
  int nw = gridDim.x * 4;
  for (int row = blockIdx.x * 4 + wid; row < Nn; row += nw) {
    float a = __half2float(agg[(size_t)row * Dd + lane]);
    float hb = fmaxf(fmaf(a, sc, sh), 0.f);
    float fv = fused[(size_t)row * Dd + lane];
    float sgm = learner_sig(hb - fv, w1, lb1v, l2, lb2v);
    float hn = hb * sgm;
    fused[(size_t)row * Dd + lane] = fv + hn;
    if (do_h) h16[(size_t)row * Dd + lane] = __float2half(hn);
  }
}

// ---------------- output map (fused) ----------------

__global__ __launch_bounds__(256) void k_outmap(const float* __restrict__ fused,
    const float* __restrict__ W1, const float* __restrict__ b1,
    const float* __restrict__ W2, const float* __restrict__ b2, float* __restrict__ out) {
  __shared__ float ws1[Dd * FIN];
  __shared__ float ws2[FIN * Dd];
  __shared__ float rf[4 * Dd];
  __shared__ float rz[4 * FIN];
  int tid = threadIdx.x, lane = tid & 63, wid = tid >> 6;
  for (int i = tid; i < Dd * FIN; i += 256) { ws1[i] = W1[i]; ws2[i] = W2[i]; }
  __syncthreads();
  float b10 = b1[lane], b11 = b1[64 + lane], b2v = b2[lane];
  int nw = gridDim.x * 4;
  for (int row = blockIdx.x * 4 + wid; row < Nn; row += nw) {
    rf[wid * Dd + lane] = fused[(size_t)row * Dd + lane];
    float a0 = b10, a1 = b11;
    #pragma unroll 16
    for (int k = 0; k < Dd; ++k) {
      float fv = rf[wid * Dd + k];
      a0 = fmaf(fv, ws1[k * FIN + lane], a0);
      a1 = fmaf(fv, ws1[k * FIN + 64 + lane], a1);
    }
    rz[wid * FIN + lane] = fmaxf(a0, 0.f);
    rz[wid * FIN + 64 + lane] = fmaxf(a1, 0.f);
    float acc = b2v;
    #pragma unroll 16
    for (int k = 0; k < FIN; ++k) acc = fmaf(rz[wid * FIN + k], ws2[k * Dd + lane], acc);
    out[(size_t)row * Dd + lane] = acc;
  }
}

// ---------------- launch ----------------

extern "C" void kernel_launch(void* const* d_in, const int* in_sizes, int n_in,
                              void* d_out, int out_size, void* d_ws, size_t ws_size,
                              hipStream_t stream) {
  const float* x      = (const float*)d_in[0];
  const int*   ei     = (const int*)d_in[1];
  const float* im_w1  = (const float*)d_in[2];
  const float* im_b1  = (const float*)d_in[3];
  const float* im_g1  = (const float*)d_in[4];
  const float* im_be1 = (const float*)d_in[5];
  const float* im_w2  = (const float*)d_in[6];
  const float* im_b2  = (const float*)d_in[7];
  const float* lw1    = (const float*)d_in[8];
  const float* lb1    = (const float*)d_in[9];
  const float* lw2    = (const float*)d_in[10];
  const float* lb2    = (const float*)d_in[11];
  const float* bw     = (const float*)d_in[12];
  const float* bb     = (const float*)d_in[13];
  const float* bg     = (const float*)d_in[14];
  const float* bbe    = (const float*)d_in[15];
  const float* om_w1  = (const float*)d_in[16];
  const float* om_b1  = (const float*)d_in[17];
  const float* om_w2  = (const float*)d_in[18];
  const float* om_b2  = (const float*)d_in[19];
  float* out = (float*)d_out;

  char* w = (char*)d_ws;
  size_t off = 0;
  auto alloc = [&](size_t bytes) -> void* {
    void* p = w + off;
    off = (off + bytes + 255) & ~(size_t)255;
    return p;
  };
  // zeroed region first
  int*   deg    = (int*)alloc((size_t)Nn * 4);
  int*   fill   = (int*)alloc((size_t)Nn * 4);
  float* statS  = (float*)alloc((size_t)9 * 128 * 4);
  float* statQ  = (float*)alloc((size_t)9 * 128 * 4);
  size_t zero_bytes = off;
  int*   rowptr = (int*)alloc((size_t)(Nn + 1) * 4);
  int2*  ce     = (int2*)alloc((size_t)ETe * 8);
  float* dinv   = (float*)alloc((size_t)Nn * 4);
  __half* t     = (__half*)alloc((size_t)Nn * FIN * 2);
  __half* h16   = (__half*)alloc((size_t)Nn * Dd * 2);
  __half* agg16 = (__half*)alloc((size_t)Nn * Dd * 2);
  float* fused  = (float*)alloc((size_t)Nn * Dd * 4);
  (void)deg; (void)fill;

  hipMemsetAsync(d_ws, 0, zero_bytes, stream);
  k_deg<<<(ETe + 255) / 256, 256, 0, stream>>>(ei, deg);
  k_scan<<<1, 1024, 0, stream>>>(deg, rowptr);
  k_dinv<<<(Nn + 255) / 256, 256, 0, stream>>>(rowptr, dinv);
  k_fill<<<(ETe + 255) / 256, 256, 0, stream>>>(ei, rowptr, fill, dinv, ce);

  k_ingemm<<<1563, 256, 0, stream>>>(x, im_w1, im_b1, t, statS, statQ);
  k_inmap2<<<2048, 256, 0, stream>>>(t, im_w2, im_b2, statS, statQ, im_g1, im_be1,
                                     lw1, lb1, lw2, lb2, fused, h16);

  for (int i = 0; i < LL; ++i) {
    float* sS = statS + (size_t)(1 + i) * 128;
    float* sQ = statQ + (size_t)(1 + i) * 128;
    k_agg<<<2048, 256, 0, stream>>>(h16, rowptr, ce, bb + i * Dd, bw + (size_t)i * Dd * Dd,
                                    agg16, sS, sQ);
    k_post<<<2048, 256, 0, stream>>>(agg16, sS, sQ, bg + i * Dd, bbe + i * Dd,
                                     lw1 + (size_t)(i + 1) * 256, lb1 + (size_t)(i + 1) * 4,
                                     lw2 + (size_t)(i + 1) * 4, lb2 + (i + 1),
                                     fused, h16, (i + 1 < LL) ? 1 : 0);
  }

  k_outmap<<<2048, 256, 0, stream>>>(fused, om_w1, om_b1, om_w2, om_b2, out);
}

// Round 4
// 974.468 us; speedup vs baseline: 2.0758x; 1.1155x over previous
//
#include <hip/hip_runtime.h>
#include <math.h>

#define Nn 50000
#define Ee 800000
#define ETe 850000   // E + N self loops
#define Dd 64
#define FIN 128
#define LL 8

typedef _Float16 f16;
typedef f16 f16x8 __attribute__((ext_vector_type(8)));
typedef float f32x4 __attribute__((ext_vector_type(4)));

// ---------------- graph build ----------------

__global__ __launch_bounds__(256) void k_deg(const int* __restrict__ ei, int* __restrict__ deg) {
  int e = blockIdx.x * 256 + threadIdx.x;
  if (e >= ETe) return;
  int dst = (e < Ee) ? ei[Ee + e] : (e - Ee);
  atomicAdd(&deg[dst], 1);
}

__global__ __launch_bounds__(1024) void k_scan(const int* __restrict__ deg, int* __restrict__ rowptr) {
  __shared__ int wsum[16];
  int tid = threadIdx.x;
  int lane = tid & 63, wid = tid >> 6;
  int carry = 0;
  for (int base = 0; base < Nn; base += 1024) {
    int i = base + tid;
    int v = (i < Nn) ? deg[i] : 0;
    int s = v;
    #pragma unroll
    for (int off = 1; off < 64; off <<= 1) {
      int t = __shfl_up(s, off, 64);
      if (lane >= off) s += t;
    }
    if (lane == 63) wsum[wid] = s;
    __syncthreads();
    if (wid == 0) {
      int ws = (lane < 16) ? wsum[lane] : 0;
      #pragma unroll
      for (int off = 1; off < 16; off <<= 1) {
        int t = __shfl_up(ws, off, 64);
        if (lane >= off) ws += t;
      }
      if (lane < 16) wsum[lane] = ws;
    }
    __syncthreads();
    int wexcl = (wid == 0) ? 0 : wsum[wid - 1];
    if (i < Nn) rowptr[i + 1] = carry + wexcl + s;
    carry += wsum[15];
    __syncthreads();
  }
  if (tid == 0) rowptr[0] = 0;
}

__global__ __launch_bounds__(256) void k_dinv(const int* __restrict__ rowptr, float* __restrict__ dinv) {
  int n = blockIdx.x * 256 + threadIdx.x;
  if (n >= Nn) return;
  int d = rowptr[n + 1] - rowptr[n];   // >= 1 (self loop)
  dinv[n] = rsqrtf((float)d);
}

__global__ __launch_bounds__(256) void k_fill(const int* __restrict__ ei, const int* __restrict__ rowptr,
                                              int* __restrict__ fill, const float* __restrict__ dinv,
                                              int2* __restrict__ ce) {
  int e = blockIdx.x * 256 + threadIdx.x;
  if (e >= ETe) return;
  int src, dst;
  if (e < Ee) { src = ei[e]; dst = ei[Ee + e]; }
  else { src = e - Ee; dst = src; }
  int pos = rowptr[dst] + atomicAdd(&fill[dst], 1);
  float w = dinv[src] * dinv[dst];
  ce[pos] = make_int2(src, __float_as_int(w));
}

// ---------------- learner MLP (per-wave, 64 lanes = 64 channels) ----------------

__device__ __forceinline__ float learner_sig(float hm, const float4 w1, const float4 lb1v,
                                             const float4 l2, float lb2v) {
  float p0 = hm * w1.x, p1 = hm * w1.y, p2 = hm * w1.z, p3 = hm * w1.w;
  #pragma unroll
  for (int off = 32; off > 0; off >>= 1) {
    p0 += __shfl_xor(p0, off, 64);
    p1 += __shfl_xor(p1, off, 64);
    p2 += __shfl_xor(p2, off, 64);
    p3 += __shfl_xor(p3, off, 64);
  }
  float z0 = p0 + lb1v.x; z0 = z0 > 0.f ? z0 : 0.2f * z0;
  float z1 = p1 + lb1v.y; z1 = z1 > 0.f ? z1 : 0.2f * z1;
  float z2 = p2 + lb1v.z; z2 = z2 > 0.f ? z2 : 0.2f * z2;
  float z3 = p3 + lb1v.w; z3 = z3 > 0.f ? z3 : 0.2f * z3;
  float lg = z0 * l2.x + z1 * l2.y + z2 * l2.z + z3 * l2.w + lb2v;
  return 1.f / (1.f + expf(-lg));
}

// ---------------- input map: t = x @ W1 + b1 (MFMA, fp16 out) + BN stats ----------------

__global__ __launch_bounds__(256) void k_ingemm(const float* __restrict__ x,
    const float* __restrict__ W1, const float* __restrict__ b1,
    f16* __restrict__ t, float* __restrict__ statS, float* __restrict__ statQ) {
  __shared__ __attribute__((aligned(16))) f16 xs[64 * 136];   // [row][k] pad 136
  __shared__ __attribute__((aligned(16))) f16 wt[128 * 136];  // wt[n][k] = W1[k][n]
  __shared__ float red[256];                                  // per-block stats (S|Q)
  int tid = threadIdx.x, lane = tid & 63, wid = tid >> 6;
  int row0 = blockIdx.x * 64;
  red[tid] = 0.f;
  for (int i = tid; i < 64 * 32; i += 256) {
    int r = i >> 5, c4 = (i & 31) * 4;
    float4 v = make_float4(0.f, 0.f, 0.f, 0.f);
    if (row0 + r < Nn) v = *(const float4*)&x[(size_t)(row0 + r) * FIN + c4];
    f16* d = &xs[r * 136 + c4];
    d[0] = (f16)v.x; d[1] = (f16)v.y; d[2] = (f16)v.z; d[3] = (f16)v.w;
  }
  for (int i = tid; i < 128 * 128; i += 256) {
    int k = i >> 7, n = i & 127;
    wt[n * 136 + k] = (f16)W1[i];
  }
  __syncthreads();
  int rl = lane & 15, kb = lane >> 4;
  f32x4 acc[8];
  #pragma unroll
  for (int i = 0; i < 8; ++i) acc[i] = (f32x4)0.f;
  #pragma unroll
  for (int ks = 0; ks < 4; ++ks) {
    f16x8 a = *(const f16x8*)&xs[(wid * 16 + rl) * 136 + ks * 32 + kb * 8];
    #pragma unroll
    for (int ct = 0; ct < 8; ++ct) {
      f16x8 b = *(const f16x8*)&wt[(ct * 16 + rl) * 136 + ks * 32 + kb * 8];
      acc[ct] = __builtin_amdgcn_mfma_f32_16x16x32_f16(a, b, acc[ct], 0, 0, 0);
    }
  }
  #pragma unroll
  for (int ct = 0; ct < 8; ++ct) {
    int col = ct * 16 + rl;
    float bv = b1[col];
    float ps = 0.f, pq = 0.f;
    #pragma unroll
    for (int r = 0; r < 4; ++r) {
      int row = row0 + wid * 16 + kb * 4 + r;
      float v = acc[ct][r] + bv;
      if (row < Nn) {
        t[(size_t)row * FIN + col] = (f16)v;
        ps += v; pq += v * v;
      }
    }
    ps += __shfl_xor(ps, 16, 64); ps += __shfl_xor(ps, 32, 64);
    pq += __shfl_xor(pq, 16, 64); pq += __shfl_xor(pq, 32, 64);
    if (kb == 0) { atomicAdd(&red[col], ps); atomicAdd(&red[128 + col], pq); }
  }
  __syncthreads();
  if (tid < 128) {
    atomicAdd(&statS[tid], red[tid]);
    atomicAdd(&statQ[tid], red[128 + tid]);
  }
}

// ---------------- h0 = relu(bn(t)) @ W2 + b2 ; learner0 ; fused = h0 ; h16 = fp16(h0) ----------------

__global__ __launch_bounds__(256) void k_inmap2(
    const f16* __restrict__ t, const float* __restrict__ W2, const float* __restrict__ b2,
    const float* __restrict__ statS, const float* __restrict__ statQ,
    const float* __restrict__ g1, const float* __restrict__ be1,
    const float* __restrict__ lw1p, const float* __restrict__ lb1p,
    const float* __restrict__ lw2p, const float* __restrict__ lb2p,
    float* __restrict__ fused, f16* __restrict__ h16) {
  __shared__ float ws[FIN * Dd];
  __shared__ __attribute__((aligned(16))) float rb[4][4 * 132];
  __shared__ float scs[FIN], shs[FIN];
  int tid = threadIdx.x, lane = tid & 63, wid = tid >> 6;
  for (int i = tid; i < FIN * Dd; i += 256) ws[i] = W2[i];
  if (tid < FIN) {
    float mu = statS[tid] * (1.f / Nn);
    float var = statQ[tid] * (1.f / Nn) - mu * mu;
    float rs = rsqrtf(var + 1e-5f);
    float scv = g1[tid] * rs;
    scs[tid] = scv; shs[tid] = be1[tid] - mu * scv;
  }
  __syncthreads();
  float4 w1 = reinterpret_cast<const float4*>(lw1p)[lane];
  float4 lb1v = *reinterpret_cast<const float4*>(lb1p);
  float4 l2 = *reinterpret_cast<const float4*>(lw2p);
  float lb2v = lb2p[0];
  float sc0 = scs[lane], sh0 = shs[lane];
  float sc1 = scs[64 + lane], sh1 = shs[64 + lane];
  float bv = b2[lane];
  int row0 = (blockIdx.x * 4 + wid) * 4;   // 3125 blocks * 16 rows = 50000 exactly
  #pragma unroll
  for (int r = 0; r < 4; ++r) {
    float v0 = (float)t[(size_t)(row0 + r) * FIN + lane];
    float v1 = (float)t[(size_t)(row0 + r) * FIN + 64 + lane];
    rb[wid][r * 132 + lane] = fmaxf(fmaf(v0, sc0, sh0), 0.f);
    rb[wid][r * 132 + 64 + lane] = fmaxf(fmaf(v1, sc1, sh1), 0.f);
  }
  asm volatile("s_waitcnt lgkmcnt(0)" ::: "memory");
  float acc[4];
  #pragma unroll
  for (int r = 0; r < 4; ++r) acc[r] = bv;
  #pragma unroll 8
  for (int kk = 0; kk < 32; ++kk) {
    float w0 = ws[(4 * kk) * Dd + lane];
    float w1v = ws[(4 * kk + 1) * Dd + lane];
    float w2v = ws[(4 * kk + 2) * Dd + lane];
    float w3v = ws[(4 * kk + 3) * Dd + lane];
    #pragma unroll
    for (int r = 0; r < 4; ++r) {
      float4 rv = *(const float4*)&rb[wid][r * 132 + 4 * kk];
      acc[r] = fmaf(rv.x, w0, acc[r]);
      acc[r] = fmaf(rv.y, w1v, acc[r]);
      acc[r] = fmaf(rv.z, w2v, acc[r]);
      acc[r] = fmaf(rv.w, w3v, acc[r]);
    }
  }
  #pragma unroll
  for (int r = 0; r < 4; ++r) {
    float sgm = learner_sig(acc[r], w1, lb1v, l2, lb2v);
    float hn = acc[r] * sgm;
    fused[(size_t)(row0 + r) * Dd + lane] = hn;
    h16[(size_t)(row0 + r) * Dd + lane] = (f16)hn;
  }
}

// ---------------- per-layer: gather + fused GEMM ----------------

// s = segsum(h16[src]*w) ; o = s @ W + bb ; agg16 = fp16(o) ; BN stats on o
__global__ __launch_bounds__(256) void k_agg(const f16* __restrict__ h16,
    const int* __restrict__ rowptr, const int2* __restrict__ ce,
    const float* __restrict__ bb, const float* __restrict__ W,
    f16* __restrict__ agg, float* __restrict__ statS, float* __restrict__ statQ) {
  __shared__ __attribute__((aligned(16))) float sA[4 * Dd];
  __shared__ float sS[256], sQ[256];
  int tid = threadIdx.x, lane = tid & 63, wid = tid >> 6;
  float wreg[64];
  #pragma unroll
  for (int k = 0; k < 64; ++k) wreg[k] = W[k * Dd + lane];
  float bv = bb[lane];
  float ls = 0.f, lq = 0.f;
  int nw = gridDim.x * 4;
  for (int row = blockIdx.x * 4 + wid; row < Nn; row += nw) {
    int urow = __builtin_amdgcn_readfirstlane(row);
    int s0 = __builtin_amdgcn_readfirstlane(rowptr[urow]);
    int s1 = __builtin_amdgcn_readfirstlane(rowptr[urow + 1]);
    const int2* ep = ce + s0;
    int n = s1 - s0;
    float a0 = 0.f, a1 = 0.f, a2 = 0.f, a3 = 0.f;
    int j = 0;
    #pragma unroll 2
    for (; j + 4 <= n; j += 4) {
      int2 e0 = ep[j], e1 = ep[j + 1], e2 = ep[j + 2], e3 = ep[j + 3];
      a0 = fmaf(__int_as_float(e0.y), (float)h16[(size_t)(unsigned)e0.x * Dd + lane], a0);
      a1 = fmaf(__int_as_float(e1.y), (float)h16[(size_t)(unsigned)e1.x * Dd + lane], a1);
      a2 = fmaf(__int_as_float(e2.y), (float)h16[(size_t)(unsigned)e2.x * Dd + lane], a2);
      a3 = fmaf(__int_as_float(e3.y), (float)h16[(size_t)(unsigned)e3.x * Dd + lane], a3);
    }
    for (; j < n; ++j) {
      int2 e = ep[j];
      a0 = fmaf(__int_as_float(e.y), (float)h16[(size_t)(unsigned)e.x * Dd + lane], a0);
    }
    float accv = (a0 + a1) + (a2 + a3);
    sA[wid * Dd + lane] = accv;
    asm volatile("s_waitcnt lgkmcnt(0)" ::: "memory");
    float o = bv;
    const float4* p = (const float4*)&sA[wid * Dd];
    #pragma unroll
    for (int kk = 0; kk < 16; ++kk) {
      float4 v = p[kk];
      o = fmaf(v.x, wreg[4 * kk], o);
      o = fmaf(v.y, wreg[4 * kk + 1], o);
      o = fmaf(v.z, wreg[4 * kk + 2], o);
      o = fmaf(v.w, wreg[4 * kk + 3], o);
    }
    agg[(size_t)row * Dd + lane] = (f16)o;
    ls += o; lq += o * o;
  }
  sS[tid] = ls; sQ[tid] = lq;
  __syncthreads();
  if (tid < 64) {
    float a = sS[tid] + sS[64 + tid] + sS[128 + tid] + sS[192 + tid];
    float q = sQ[tid] + sQ[64 + tid] + sQ[128 + tid] + sQ[192 + tid];
    atomicAdd(&statS[tid], a);
    atomicAdd(&statQ[tid], q);
  }
}

// h = relu(bn(agg)); s = learner(h - fused); hn = h*s; fused += hn
// mode 1: h16 = fp16(hn)   mode 2 (last layer): h16 = fp16(fused_new)
__global__ __launch_bounds__(256) void k_post(const f16* __restrict__ agg,
    const float* __restrict__ statS, const float* __restrict__ statQ,
    const float* __restrict__ gamma, const float* __restrict__ beta,
    const float* __restrict__ lw1p, const float* __restrict__ lb1p,
    const float* __restrict__ lw2p, const float* __restrict__ lb2p,
    float* __restrict__ fused, f16* __restrict__ h16, int mode) {
  __shared__ float scs[Dd], shs[Dd];
  int tid = threadIdx.x, lane = tid & 63, wid = tid >> 6;
  if (tid < Dd) {
    float mu = statS[tid] * (1.f / Nn);
    float var = statQ[tid] * (1.f / Nn) - mu * mu;
    float rs = rsqrtf(var + 1e-5f);
    float scv = gamma[tid] * rs;
    scs[tid] = scv; shs[tid] = beta[tid] - mu * scv;
  }
  __syncthreads();
  float4 w1 = reinterpret_cast<const float4*>(lw1p)[lane];
  float4 lb1v = *reinterpret_cast<const float4*>(lb1p);
  float4 l2 = *reinterpret_cast<const float4*>(lw2p);
  float lb2v = lb2p[0];
  float sc = scs[lane], sh = shs[lane];
  int nw = gridDim.x * 4;
  for (int row = blockIdx.x * 4 + wid; row < Nn; row += nw) {
    float a = (float)agg[(size_t)row * Dd + lane];
    float hb = fmaxf(fmaf(a, sc, sh), 0.f);
    float fv = fused[(size_t)row * Dd + lane];
    float sgm = learner_sig(hb - fv, w1, lb1v, l2, lb2v);
    float hn = hb * sgm;
    float fnew = fv + hn;
    fused[(size_t)row * Dd + lane] = fnew;
    if (mode == 1) h16[(size_t)row * Dd + lane] = (f16)hn;
    else h16[(size_t)row * Dd + lane] = (f16)fnew;
  }
}

// ---------------- output map (MFMA, both GEMMs fused) ----------------

__global__ __launch_bounds__(256) void k_outmap(const f16* __restrict__ fused16,
    const float* __restrict__ W1, const float* __restrict__ b1,
    const float* __restrict__ W2, const float* __restrict__ b2, float* __restrict__ out) {
  __shared__ __attribute__((aligned(16))) f16 fs[64 * 72];    // A tile [row][k<64]
  __shared__ __attribute__((aligned(16))) f16 w1t[128 * 72];  // w1t[n][k] = W1[k][n]
  __shared__ __attribute__((aligned(16))) f16 w2t[64 * 136];  // w2t[n][k] = W2[k][n]
  __shared__ __attribute__((aligned(16))) f16 zs[64 * 136];   // z rows [row][k<128]
  int tid = threadIdx.x, lane = tid & 63, wid = tid >> 6;
  int row0 = blockIdx.x * 64;
  for (int i = tid; i < 64 * 64; i += 256) {
    int r = i >> 6, c = i & 63;
    fs[r * 72 + c] = (row0 + r < Nn) ? fused16[(size_t)(row0 + r) * Dd + c] : (f16)0.f;
  }
  for (int i = tid; i < 64 * 128; i += 256) {
    int k = i >> 7, n = i & 127;
    w1t[n * 72 + k] = (f16)W1[i];
  }
  for (int i = tid; i < 128 * 64; i += 256) {
    int k = i >> 6, n = i & 63;
    w2t[n * 136 + k] = (f16)W2[i];
  }
  __syncthreads();
  int rl = lane & 15, kb = lane >> 4;
  f32x4 acc1[8];
  #pragma unroll
  for (int i = 0; i < 8; ++i) acc1[i] = (f32x4)0.f;
  #pragma unroll
  for (int ks = 0; ks < 2; ++ks) {
    f16x8 a = *(const f16x8*)&fs[(wid * 16 + rl) * 72 + ks * 32 + kb * 8];
    #pragma unroll
    for (int ct = 0; ct < 8; ++ct) {
      f16x8 b = *(const f16x8*)&w1t[(ct * 16 + rl) * 72 + ks * 32 + kb * 8];
      acc1[ct] = __builtin_amdgcn_mfma_f32_16x16x32_f16(a, b, acc1[ct], 0, 0, 0);
    }
  }
  #pragma unroll
  for (int ct = 0; ct < 8; ++ct) {
    float bv = b1[ct * 16 + rl];
    #pragma unroll
    for (int r = 0; r < 4; ++r) {
      float z = fmaxf(acc1[ct][r] + bv, 0.f);
      zs[(wid * 16 + kb * 4 + r) * 136 + ct * 16 + rl] = (f16)z;
    }
  }
  __syncthreads();
  f32x4 acc2[4];
  #pragma unroll
  for (int i = 0; i < 4; ++i) acc2[i] = (f32x4)0.f;
  #pragma unroll
  for (int ks = 0; ks < 4; ++ks) {
    f16x8 a = *(const f16x8*)&zs[(wid * 16 + rl) * 136 + ks * 32 + kb * 8];
    #pragma unroll
    for (int ct = 0; ct < 4; ++ct) {
      f16x8 b = *(const f16x8*)&w2t[(ct * 16 + rl) * 136 + ks * 32 + kb * 8];
      acc2[ct] = __builtin_amdgcn_mfma_f32_16x16x32_f16(a, b, acc2[ct], 0, 0, 0);
    }
  }
  #pragma unroll
  for (int ct = 0; ct < 4; ++ct) {
    float bv = b2[ct * 16 + rl];
    #pragma unroll
    for (int r = 0; r < 4; ++r) {
      int row = row0 + wid * 16 + kb * 4 + r;
      if (row < Nn) out[(size_t)row * Dd + ct * 16 + rl] = acc2[ct][r] + bv;
    }
  }
}

// ---------------- launch ----------------

extern "C" void kernel_launch(void* const* d_in, const int* in_sizes, int n_in,
                              void* d_out, int out_size, void* d_ws, size_t ws_size,
                              hipStream_t stream) {
  const float* x      = (const float*)d_in[0];
  const int*   ei     = (const int*)d_in[1];
  const float* im_w1  = (const float*)d_in[2];
  const float* im_b1  = (const float*)d_in[3];
  const float* im_g1  = (const float*)d_in[4];
  const float* im_be1 = (const float*)d_in[5];
  const float* im_w2  = (const float*)d_in[6];
  const float* im_b2  = (const float*)d_in[7];
  const float* lw1    = (const float*)d_in[8];
  const float* lb1    = (const float*)d_in[9];
  const float* lw2    = (const float*)d_in[10];
  const float* lb2    = (const float*)d_in[11];
  const float* bw     = (const float*)d_in[12];
  const float* bb     = (const float*)d_in[13];
  const float* bg     = (const float*)d_in[14];
  const float* bbe    = (const float*)d_in[15];
  const float* om_w1  = (const float*)d_in[16];
  const float* om_b1  = (const float*)d_in[17];
  const float* om_w2  = (const float*)d_in[18];
  const float* om_b2  = (const float*)d_in[19];
  float* out = (float*)d_out;

  char* w = (char*)d_ws;
  size_t off = 0;
  auto alloc = [&](size_t bytes) -> void* {
    void* p = w + off;
    off = (off + bytes + 255) & ~(size_t)255;
    return p;
  };
  // zeroed region first
  int*   deg    = (int*)alloc((size_t)Nn * 4);
  int*   fill   = (int*)alloc((size_t)Nn * 4);
  float* statS  = (float*)alloc((size_t)9 * 128 * 4);
  float* statQ  = (float*)alloc((size_t)9 * 128 * 4);
  size_t zero_bytes = off;
  int*   rowptr = (int*)alloc((size_t)(Nn + 1) * 4);
  int2*  ce     = (int2*)alloc((size_t)ETe * 8);
  float* dinv   = (float*)alloc((size_t)Nn * 4);
  f16*   t      = (f16*)alloc((size_t)Nn * FIN * 2);
  f16*   h16    = (f16*)alloc((size_t)Nn * Dd * 2);
  f16*   agg16  = (f16*)alloc((size_t)Nn * Dd * 2);
  float* fused  = (float*)alloc((size_t)Nn * Dd * 4);
  (void)deg; (void)fill;

  hipMemsetAsync(d_ws, 0, zero_bytes, stream);
  k_deg<<<(ETe + 255) / 256, 256, 0, stream>>>(ei, deg);
  k_scan<<<1, 1024, 0, stream>>>(deg, rowptr);
  k_dinv<<<(Nn + 255) / 256, 256, 0, stream>>>(rowptr, dinv);
  k_fill<<<(ETe + 255) / 256, 256, 0, stream>>>(ei, rowptr, fill, dinv, ce);

  k_ingemm<<<782, 256, 0, stream>>>(x, im_w1, im_b1, t, statS, statQ);
  k_inmap2<<<3125, 256, 0, stream>>>(t, im_w2, im_b2, statS, statQ, im_g1, im_be1,
                                     lw1, lb1, lw2, lb2, fused, h16);

  for (int i = 0; i < LL; ++i) {
    float* sS = statS + (size_t)(1 + i) * 128;
    float* sQ = statQ + (size_t)(1 + i) * 128;
    k_agg<<<2048, 256, 0, stream>>>(h16, rowptr, ce, bb + i * Dd, bw + (size_t)i * Dd * Dd,
                                    agg16, sS, sQ);
    k_post<<<2048, 256, 0, stream>>>(agg16, sS, sQ, bg + i * Dd, bbe + i * Dd,
                                     lw1 + (size_t)(i + 1) * 256, lb1 + (size_t)(i + 1) * 4,
                                     lw2 + (size_t)(i + 1) * 4, lb2 + (i + 1),
                                     fused, h16, (i + 1 < LL) ? 1 : 2);
  }

  k_outmap<<<782, 256, 0, stream>>>(h16, om_w1, om_b1, om_w2, om_b2, out);
}

// Round 5
// 683.549 us; speedup vs baseline: 2.9593x; 1.4256x over previous
//
#include <hip/hip_runtime.h>
#include <math.h>

#define Nn 50000
#define Ee 800000
#define ETe 850000   // E + N self loops
#define Dd 64
#define FIN 128
#define LL 8

typedef _Float16 f16;
typedef f16 f16x8 __attribute__((ext_vector_type(8)));
typedef float f32x4 __attribute__((ext_vector_type(4)));

// ---------------- graph build ----------------

__global__ __launch_bounds__(256) void k_deg(const int* __restrict__ ei, int* __restrict__ deg) {
  int e = blockIdx.x * 256 + threadIdx.x;
  if (e >= ETe) return;
  int dst = (e < Ee) ? ei[Ee + e] : (e - Ee);
  atomicAdd(&deg[dst], 1);
}

__global__ __launch_bounds__(1024) void k_scan(const int* __restrict__ deg, int* __restrict__ rowptr) {
  __shared__ int wsum[16];
  int tid = threadIdx.x;
  int lane = tid & 63, wid = tid >> 6;
  int carry = 0;
  for (int base = 0; base < Nn; base += 1024) {
    int i = base + tid;
    int v = (i < Nn) ? deg[i] : 0;
    int s = v;
    #pragma unroll
    for (int off = 1; off < 64; off <<= 1) {
      int t = __shfl_up(s, off, 64);
      if (lane >= off) s += t;
    }
    if (lane == 63) wsum[wid] = s;
    __syncthreads();
    if (wid == 0) {
      int ws = (lane < 16) ? wsum[lane] : 0;
      #pragma unroll
      for (int off = 1; off < 16; off <<= 1) {
        int t = __shfl_up(ws, off, 64);
        if (lane >= off) ws += t;
      }
      if (lane < 16) wsum[lane] = ws;
    }
    __syncthreads();
    int wexcl = (wid == 0) ? 0 : wsum[wid - 1];
    if (i < Nn) rowptr[i + 1] = carry + wexcl + s;
    carry += wsum[15];
    __syncthreads();
  }
  if (tid == 0) rowptr[0] = 0;
}

__global__ __launch_bounds__(256) void k_dinv(const int* __restrict__ rowptr, float* __restrict__ dinv) {
  int n = blockIdx.x * 256 + threadIdx.x;
  if (n >= Nn) return;
  int d = rowptr[n + 1] - rowptr[n];   // >= 1 (self loop)
  dinv[n] = rsqrtf((float)d);
}

__global__ __launch_bounds__(256) void k_fill(const int* __restrict__ ei, const int* __restrict__ rowptr,
                                              int* __restrict__ fill, const float* __restrict__ dinv,
                                              int2* __restrict__ ce) {
  int e = blockIdx.x * 256 + threadIdx.x;
  if (e >= ETe) return;
  int src, dst;
  if (e < Ee) { src = ei[e]; dst = ei[Ee + e]; }
  else { src = e - Ee; dst = src; }
  int pos = rowptr[dst] + atomicAdd(&fill[dst], 1);
  float w = dinv[src] * dinv[dst];
  ce[pos] = make_int2(src, __float_as_int(w));
}

// ---------------- learner MLP (per-wave, 64 lanes = 64 channels) — used by inmap2 ----------------

__device__ __forceinline__ float learner_sig(float hm, const float4 w1, const float4 lb1v,
                                             const float4 l2, float lb2v) {
  float p0 = hm * w1.x, p1 = hm * w1.y, p2 = hm * w1.z, p3 = hm * w1.w;
  #pragma unroll
  for (int off = 32; off > 0; off >>= 1) {
    p0 += __shfl_xor(p0, off, 64);
    p1 += __shfl_xor(p1, off, 64);
    p2 += __shfl_xor(p2, off, 64);
    p3 += __shfl_xor(p3, off, 64);
  }
  float z0 = p0 + lb1v.x; z0 = z0 > 0.f ? z0 : 0.2f * z0;
  float z1 = p1 + lb1v.y; z1 = z1 > 0.f ? z1 : 0.2f * z1;
  float z2 = p2 + lb1v.z; z2 = z2 > 0.f ? z2 : 0.2f * z2;
  float z3 = p3 + lb1v.w; z3 = z3 > 0.f ? z3 : 0.2f * z3;
  float lg = z0 * l2.x + z1 * l2.y + z2 * l2.z + z3 * l2.w + lb2v;
  return 1.f / (1.f + expf(-lg));
}

// ---------------- input map: t = x @ W1 + b1 (MFMA, fp16 out) + BN stats ----------------

__global__ __launch_bounds__(256) void k_ingemm(const float* __restrict__ x,
    const float* __restrict__ W1, const float* __restrict__ b1,
    f16* __restrict__ t, float* __restrict__ statS, float* __restrict__ statQ) {
  __shared__ __attribute__((aligned(16))) f16 xs[64 * 136];   // [row][k] pad 136
  __shared__ __attribute__((aligned(16))) f16 wt[128 * 136];  // wt[n][k] = W1[k][n]
  __shared__ float red[256];                                  // per-block stats (S|Q)
  int tid = threadIdx.x, lane = tid & 63, wid = tid >> 6;
  int row0 = blockIdx.x * 64;
  red[tid] = 0.f;
  for (int i = tid; i < 64 * 32; i += 256) {
    int r = i >> 5, c4 = (i & 31) * 4;
    float4 v = make_float4(0.f, 0.f, 0.f, 0.f);
    if (row0 + r < Nn) v = *(const float4*)&x[(size_t)(row0 + r) * FIN + c4];
    f16* d = &xs[r * 136 + c4];
    d[0] = (f16)v.x; d[1] = (f16)v.y; d[2] = (f16)v.z; d[3] = (f16)v.w;
  }
  for (int i = tid; i < 128 * 128; i += 256) {
    int k = i >> 7, n = i & 127;
    wt[n * 136 + k] = (f16)W1[i];
  }
  __syncthreads();
  int rl = lane & 15, kb = lane >> 4;
  f32x4 acc[8];
  #pragma unroll
  for (int i = 0; i < 8; ++i) acc[i] = (f32x4)0.f;
  #pragma unroll
  for (int ks = 0; ks < 4; ++ks) {
    f16x8 a = *(const f16x8*)&xs[(wid * 16 + rl) * 136 + ks * 32 + kb * 8];
    #pragma unroll
    for (int ct = 0; ct < 8; ++ct) {
      f16x8 b = *(const f16x8*)&wt[(ct * 16 + rl) * 136 + ks * 32 + kb * 8];
      acc[ct] = __builtin_amdgcn_mfma_f32_16x16x32_f16(a, b, acc[ct], 0, 0, 0);
    }
  }
  #pragma unroll
  for (int ct = 0; ct < 8; ++ct) {
    int col = ct * 16 + rl;
    float bv = b1[col];
    float ps = 0.f, pq = 0.f;
    #pragma unroll
    for (int r = 0; r < 4; ++r) {
      int row = row0 + wid * 16 + kb * 4 + r;
      float v = acc[ct][r] + bv;
      if (row < Nn) {
        t[(size_t)row * FIN + col] = (f16)v;
        ps += v; pq += v * v;
      }
    }
    ps += __shfl_xor(ps, 16, 64); ps += __shfl_xor(ps, 32, 64);
    pq += __shfl_xor(pq, 16, 64); pq += __shfl_xor(pq, 32, 64);
    if (kb == 0) { atomicAdd(&red[col], ps); atomicAdd(&red[128 + col], pq); }
  }
  __syncthreads();
  if (tid < 128) {
    atomicAdd(&statS[tid], red[tid]);
    atomicAdd(&statQ[tid], red[128 + tid]);
  }
}

// ---------------- h0 = relu(bn(t)) @ W2 + b2 ; learner0 ; fused = h0 ; h16 = fp16(h0) ----------------

__global__ __launch_bounds__(256) void k_inmap2(
    const f16* __restrict__ t, const float* __restrict__ W2, const float* __restrict__ b2,
    const float* __restrict__ statS, const float* __restrict__ statQ,
    const float* __restrict__ g1, const float* __restrict__ be1,
    const float* __restrict__ lw1p, const float* __restrict__ lb1p,
    const float* __restrict__ lw2p, const float* __restrict__ lb2p,
    float* __restrict__ fused, f16* __restrict__ h16) {
  __shared__ float ws[FIN * Dd];
  __shared__ __attribute__((aligned(16))) float rb[4][4 * 132];
  __shared__ float scs[FIN], shs[FIN];
  int tid = threadIdx.x, lane = tid & 63, wid = tid >> 6;
  for (int i = tid; i < FIN * Dd; i += 256) ws[i] = W2[i];
  if (tid < FIN) {
    float mu = statS[tid] * (1.f / Nn);
    float var = statQ[tid] * (1.f / Nn) - mu * mu;
    float rs = rsqrtf(var + 1e-5f);
    float scv = g1[tid] * rs;
    scs[tid] = scv; shs[tid] = be1[tid] - mu * scv;
  }
  __syncthreads();
  float4 w1 = reinterpret_cast<const float4*>(lw1p)[lane];
  float4 lb1v = *reinterpret_cast<const float4*>(lb1p);
  float4 l2 = *reinterpret_cast<const float4*>(lw2p);
  float lb2v = lb2p[0];
  float sc0 = scs[lane], sh0 = shs[lane];
  float sc1 = scs[64 + lane], sh1 = shs[64 + lane];
  float bv = b2[lane];
  int row0 = (blockIdx.x * 4 + wid) * 4;   // 3125 blocks * 16 rows = 50000 exactly
  #pragma unroll
  for (int r = 0; r < 4; ++r) {
    float v0 = (float)t[(size_t)(row0 + r) * FIN + lane];
    float v1 = (float)t[(size_t)(row0 + r) * FIN + 64 + lane];
    rb[wid][r * 132 + lane] = fmaxf(fmaf(v0, sc0, sh0), 0.f);
    rb[wid][r * 132 + 64 + lane] = fmaxf(fmaf(v1, sc1, sh1), 0.f);
  }
  asm volatile("s_waitcnt lgkmcnt(0)" ::: "memory");
  float acc[4];
  #pragma unroll
  for (int r = 0; r < 4; ++r) acc[r] = bv;
  #pragma unroll 8
  for (int kk = 0; kk < 32; ++kk) {
    float w0 = ws[(4 * kk) * Dd + lane];
    float w1v = ws[(4 * kk + 1) * Dd + lane];
    float w2v = ws[(4 * kk + 2) * Dd + lane];
    float w3v = ws[(4 * kk + 3) * Dd + lane];
    #pragma unroll
    for (int r = 0; r < 4; ++r) {
      float4 rv = *(const float4*)&rb[wid][r * 132 + 4 * kk];
      acc[r] = fmaf(rv.x, w0, acc[r]);
      acc[r] = fmaf(rv.y, w1v, acc[r]);
      acc[r] = fmaf(rv.z, w2v, acc[r]);
      acc[r] = fmaf(rv.w, w3v, acc[r]);
    }
  }
  #pragma unroll
  for (int r = 0; r < 4; ++r) {
    float sgm = learner_sig(acc[r], w1, lb1v, l2, lb2v);
    float hn = acc[r] * sgm;
    fused[(size_t)(row0 + r) * Dd + lane] = hn;
    h16[(size_t)(row0 + r) * Dd + lane] = (f16)hn;
  }
}

// ---------------- per-layer: gather (8-lane groups) + MFMA GEMM + stats ----------------

__global__ __launch_bounds__(256) void k_agg(const f16* __restrict__ h16,
    const int* __restrict__ rowptr, const int2* __restrict__ ce,
    const float* __restrict__ bb, const float* __restrict__ W,
    f16* __restrict__ agg, float* __restrict__ statS, float* __restrict__ statQ) {
  __shared__ __attribute__((aligned(16))) f16 sumt[64 * 72];  // [row][ch] pad 72
  __shared__ __attribute__((aligned(16))) f16 wt[64 * 72];    // wt[n][k] = W[k][n]
  __shared__ float red[128];                                  // S[64] | Q[64]
  int tid = threadIdx.x, lane = tid & 63, wid = tid >> 6;
  int row0 = blockIdx.x * 64;
  for (int i = tid; i < Dd * Dd; i += 256) {
    int k = i >> 6, n = i & 63;
    wt[n * 72 + k] = (f16)W[i];
  }
  if (tid < 128) red[tid] = 0.f;

  // gather: 8 groups of 8 lanes; group g handles rows {2g, 2g+1} of this wave's strip
  int g = lane >> 3, cl = lane & 7;
  #pragma unroll
  for (int rr = 0; rr < 2; ++rr) {
    int lrow = wid * 16 + g * 2 + rr;
    int row = row0 + lrow;
    float a[8];
    #pragma unroll
    for (int c = 0; c < 8; ++c) a[c] = 0.f;
    if (row < Nn) {
      int s0 = rowptr[row], s1 = rowptr[row + 1];
      int2 e0 = ce[s0], e1 = ce[s0 + 1];
      for (int j = s0; j < s1; j += 2) {
        int2 f0 = ce[j + 2], f1 = ce[j + 3];       // prefetch (ce padded)
        bool has1 = (j + 1 < s1);
        float w0 = __int_as_float(e0.y);
        float w1 = has1 ? __int_as_float(e1.y) : 0.f;
        unsigned c0 = (unsigned)e0.x;
        unsigned c1 = has1 ? (unsigned)e1.x : 0u;
        f16x8 v0 = *(const f16x8*)(h16 + (size_t)c0 * Dd + cl * 8);
        f16x8 v1 = *(const f16x8*)(h16 + (size_t)c1 * Dd + cl * 8);
        #pragma unroll
        for (int c = 0; c < 8; ++c) a[c] = fmaf((float)v0[c], w0, a[c]);
        #pragma unroll
        for (int c = 0; c < 8; ++c) a[c] = fmaf((float)v1[c], w1, a[c]);
        e0 = f0; e1 = f1;
      }
    }
    f16x8 hv;
    #pragma unroll
    for (int c = 0; c < 8; ++c) hv[c] = (f16)a[c];
    *(f16x8*)&sumt[lrow * 72 + cl * 8] = hv;
  }
  __syncthreads();

  // MFMA: o = sum @ W + bb for this wave's 16-row strip
  int rl = lane & 15, kb = lane >> 4;
  f32x4 acc4[4];
  #pragma unroll
  for (int i = 0; i < 4; ++i) acc4[i] = (f32x4)0.f;
  #pragma unroll
  for (int ks = 0; ks < 2; ++ks) {
    f16x8 af = *(const f16x8*)&sumt[(wid * 16 + rl) * 72 + ks * 32 + kb * 8];
    #pragma unroll
    for (int ct = 0; ct < 4; ++ct) {
      f16x8 bf = *(const f16x8*)&wt[(ct * 16 + rl) * 72 + ks * 32 + kb * 8];
      acc4[ct] = __builtin_amdgcn_mfma_f32_16x16x32_f16(af, bf, acc4[ct], 0, 0, 0);
    }
  }
  #pragma unroll
  for (int ct = 0; ct < 4; ++ct) {
    float bv = bb[ct * 16 + rl];
    float s = 0.f, q = 0.f;
    #pragma unroll
    for (int r = 0; r < 4; ++r) {
      int row = row0 + wid * 16 + kb * 4 + r;
      float o = acc4[ct][r] + bv;
      if (row < Nn) {
        agg[(size_t)row * Dd + ct * 16 + rl] = (f16)o;
        s += o; q += o * o;
      }
    }
    s += __shfl_xor(s, 16, 64); s += __shfl_xor(s, 32, 64);
    q += __shfl_xor(q, 16, 64); q += __shfl_xor(q, 32, 64);
    if (kb == 0) { atomicAdd(&red[ct * 16 + rl], s); atomicAdd(&red[64 + ct * 16 + rl], q); }
  }
  __syncthreads();
  if (tid < 64) {
    atomicAdd(&statS[tid], red[tid]);
    atomicAdd(&statQ[tid], red[64 + tid]);
  }
}

// ---------------- post: BN + MFMA learner + gate + residual ----------------

__global__ __launch_bounds__(256) void k_post(const f16* __restrict__ agg,
    const float* __restrict__ statS, const float* __restrict__ statQ,
    const float* __restrict__ gamma, const float* __restrict__ beta,
    const float* __restrict__ lw1p, const float* __restrict__ lb1p,
    const float* __restrict__ lw2p, const float* __restrict__ lb2p,
    float* __restrict__ fused, f16* __restrict__ h16, int mode) {
  __shared__ __attribute__((aligned(16))) f16 dT[64 * 72];   // d = h - fused, [row][ch]
  __shared__ __attribute__((aligned(16))) f16 wt1[16 * 72];  // wt1[n][ch] = lw1[ch][n] (n<4)
  __shared__ float scs[Dd], shs[Dd], sg[64];
  int tid = threadIdx.x, lane = tid & 63, wid = tid >> 6;
  int row0 = blockIdx.x * 64;
  if (tid < Dd) {
    float mu = statS[tid] * (1.f / Nn);
    float var = statQ[tid] * (1.f / Nn) - mu * mu;
    float rs = rsqrtf(var + 1e-5f);
    float scv = gamma[tid] * rs;
    scs[tid] = scv; shs[tid] = beta[tid] - mu * scv;
  }
  for (int i = tid; i < 16 * 64; i += 256) {
    int n = i & 15, k = i >> 4;
    wt1[n * 72 + k] = (n < 4) ? (f16)lw1p[k * 4 + n] : (f16)0.f;
  }
  __syncthreads();
  float sc = scs[lane], sh = shs[lane];
  float hb[16], fv[16];
  #pragma unroll
  for (int r = 0; r < 16; ++r) {
    int row = row0 + wid * 16 + r;
    float a = 0.f, f = 0.f;
    if (row < Nn) {
      a = (float)agg[(size_t)row * Dd + lane];
      f = fused[(size_t)row * Dd + lane];
    }
    float h = fmaxf(fmaf(a, sc, sh), 0.f);
    hb[r] = h; fv[r] = f;
    dT[(wid * 16 + r) * 72 + lane] = (f16)(h - f);
  }
  // learner via MFMA (wave-local: dT rows written by this wave)
  int rl = lane & 15, kb = lane >> 4;
  f32x4 zacc = (f32x4)0.f;
  #pragma unroll
  for (int ks = 0; ks < 2; ++ks) {
    f16x8 af = *(const f16x8*)&dT[(wid * 16 + rl) * 72 + ks * 32 + kb * 8];
    f16x8 bf = *(const f16x8*)&wt1[rl * 72 + ks * 32 + kb * 8];
    zacc = __builtin_amdgcn_mfma_f32_16x16x32_f16(af, bf, zacc, 0, 0, 0);
  }
  float lb1v = (rl < 4) ? lb1p[rl] : 0.f;
  float lw2v = (rl < 4) ? lw2p[rl] : 0.f;
  float lb2v = lb2p[0];
  #pragma unroll
  for (int r = 0; r < 4; ++r) {
    float z = zacc[r] + lb1v;
    z = (z > 0.f) ? z : 0.2f * z;
    float p = z * lw2v;
    p += __shfl_xor(p, 1, 64);
    p += __shfl_xor(p, 2, 64);
    float sgm = 1.f / (1.f + expf(-(p + lb2v)));
    if (rl == 0) sg[wid * 16 + kb * 4 + r] = sgm;
  }
  // wave-local sg read-after-write (in-order LDS within a wave)
  #pragma unroll
  for (int r = 0; r < 16; ++r) {
    int row = row0 + wid * 16 + r;
    if (row < Nn) {
      float sgm = sg[wid * 16 + r];
      float hn = hb[r] * sgm;
      float fn = fv[r] + hn;
      fused[(size_t)row * Dd + lane] = fn;
      h16[(size_t)row * Dd + lane] = (f16)((mode == 1) ? hn : fn);
    }
  }
}

// ---------------- output map (MFMA, both GEMMs fused) ----------------

__global__ __launch_bounds__(256) void k_outmap(const f16* __restrict__ fused16,
    const float* __restrict__ W1, const float* __restrict__ b1,
    const float* __restrict__ W2, const float* __restrict__ b2, float* __restrict__ out) {
  __shared__ __attribute__((aligned(16))) f16 fs[64 * 72];    // A tile [row][k<64]
  __shared__ __attribute__((aligned(16))) f16 w1t[128 * 72];  // w1t[n][k] = W1[k][n]
  __shared__ __attribute__((aligned(16))) f16 w2t[64 * 136];  // w2t[n][k] = W2[k][n]
  __shared__ __attribute__((aligned(16))) f16 zs[64 * 136];   // z rows [row][k<128]
  int tid = threadIdx.x, lane = tid & 63, wid = tid >> 6;
  int row0 = blockIdx.x * 64;
  for (int i = tid; i < 64 * 64; i += 256) {
    int r = i >> 6, c = i & 63;
    fs[r * 72 + c] = (row0 + r < Nn) ? fused16[(size_t)(row0 + r) * Dd + c] : (f16)0.f;
  }
  for (int i = tid; i < 64 * 128; i += 256) {
    int k = i >> 7, n = i & 127;
    w1t[n * 72 + k] = (f16)W1[i];
  }
  for (int i = tid; i < 128 * 64; i += 256) {
    int k = i >> 6, n = i & 63;
    w2t[n * 136 + k] = (f16)W2[i];
  }
  __syncthreads();
  int rl = lane & 15, kb = lane >> 4;
  f32x4 acc1[8];
  #pragma unroll
  for (int i = 0; i < 8; ++i) acc1[i] = (f32x4)0.f;
  #pragma unroll
  for (int ks = 0; ks < 2; ++ks) {
    f16x8 a = *(const f16x8*)&fs[(wid * 16 + rl) * 72 + ks * 32 + kb * 8];
    #pragma unroll
    for (int ct = 0; ct < 8; ++ct) {
      f16x8 b = *(const f16x8*)&w1t[(ct * 16 + rl) * 72 + ks * 32 + kb * 8];
      acc1[ct] = __builtin_amdgcn_mfma_f32_16x16x32_f16(a, b, acc1[ct], 0, 0, 0);
    }
  }
  #pragma unroll
  for (int ct = 0; ct < 8; ++ct) {
    float bv = b1[ct * 16 + rl];
    #pragma unroll
    for (int r = 0; r < 4; ++r) {
      float z = fmaxf(acc1[ct][r] + bv, 0.f);
      zs[(wid * 16 + kb * 4 + r) * 136 + ct * 16 + rl] = (f16)z;
    }
  }
  __syncthreads();
  f32x4 acc2[4];
  #pragma unroll
  for (int i = 0; i < 4; ++i) acc2[i] = (f32x4)0.f;
  #pragma unroll
  for (int ks = 0; ks < 4; ++ks) {
    f16x8 a = *(const f16x8*)&zs[(wid * 16 + rl) * 136 + ks * 32 + kb * 8];
    #pragma unroll
    for (int ct = 0; ct < 4; ++ct) {
      f16x8 b = *(const f16x8*)&w2t[(ct * 16 + rl) * 136 + ks * 32 + kb * 8];
      acc2[ct] = __builtin_amdgcn_mfma_f32_16x16x32_f16(a, b, acc2[ct], 0, 0, 0);
    }
  }
  #pragma unroll
  for (int ct = 0; ct < 4; ++ct) {
    float bv = b2[ct * 16 + rl];
    #pragma unroll
    for (int r = 0; r < 4; ++r) {
      int row = row0 + wid * 16 + kb * 4 + r;
      if (row < Nn) out[(size_t)row * Dd + ct * 16 + rl] = acc2[ct][r] + bv;
    }
  }
}

// ---------------- launch ----------------

extern "C" void kernel_launch(void* const* d_in, const int* in_sizes, int n_in,
                              void* d_out, int out_size, void* d_ws, size_t ws_size,
                              hipStream_t stream) {
  const float* x      = (const float*)d_in[0];
  const int*   ei     = (const int*)d_in[1];
  const float* im_w1  = (const float*)d_in[2];
  const float* im_b1  = (const float*)d_in[3];
  const float* im_g1  = (const float*)d_in[4];
  const float* im_be1 = (const float*)d_in[5];
  const float* im_w2  = (const float*)d_in[6];
  const float* im_b2  = (const float*)d_in[7];
  const float* lw1    = (const float*)d_in[8];
  const float* lb1    = (const float*)d_in[9];
  const float* lw2    = (const float*)d_in[10];
  const float* lb2    = (const float*)d_in[11];
  const float* bw     = (const float*)d_in[12];
  const float* bb     = (const float*)d_in[13];
  const float* bg     = (const float*)d_in[14];
  const float* bbe    = (const float*)d_in[15];
  const float* om_w1  = (const float*)d_in[16];
  const float* om_b1  = (const float*)d_in[17];
  const float* om_w2  = (const float*)d_in[18];
  const float* om_b2  = (const float*)d_in[19];
  float* out = (float*)d_out;

  char* w = (char*)d_ws;
  size_t off = 0;
  auto alloc = [&](size_t bytes) -> void* {
    void* p = w + off;
    off = (off + bytes + 255) & ~(size_t)255;
    return p;
  };
  // zeroed region first
  int*   deg    = (int*)alloc((size_t)Nn * 4);
  int*   fill   = (int*)alloc((size_t)Nn * 4);
  float* statS  = (float*)alloc((size_t)9 * 128 * 4);
  float* statQ  = (float*)alloc((size_t)9 * 128 * 4);
  size_t zero_bytes = off;
  int*   rowptr = (int*)alloc((size_t)(Nn + 1) * 4);
  int2*  ce     = (int2*)alloc((size_t)(ETe + 8) * 8);   // +pad for prefetch
  float* dinv   = (float*)alloc((size_t)Nn * 4);
  f16*   t      = (f16*)alloc((size_t)Nn * FIN * 2);
  f16*   h16    = (f16*)alloc((size_t)Nn * Dd * 2);
  f16*   agg16  = (f16*)alloc((size_t)Nn * Dd * 2);
  float* fused  = (float*)alloc((size_t)Nn * Dd * 4);
  (void)deg; (void)fill;

  hipMemsetAsync(d_ws, 0, zero_bytes, stream);
  k_deg<<<(ETe + 255) / 256, 256, 0, stream>>>(ei, deg);
  k_scan<<<1, 1024, 0, stream>>>(deg, rowptr);
  k_dinv<<<(Nn + 255) / 256, 256, 0, stream>>>(rowptr, dinv);
  k_fill<<<(ETe + 255) / 256, 256, 0, stream>>>(ei, rowptr, fill, dinv, ce);

  k_ingemm<<<782, 256, 0, stream>>>(x, im_w1, im_b1, t, statS, statQ);
  k_inmap2<<<3125, 256, 0, stream>>>(t, im_w2, im_b2, statS, statQ, im_g1, im_be1,
                                     lw1, lb1, lw2, lb2, fused, h16);

  for (int i = 0; i < LL; ++i) {
    float* sS = statS + (size_t)(1 + i) * 128;
    float* sQ = statQ + (size_t)(1 + i) * 128;
    k_agg<<<782, 256, 0, stream>>>(h16, rowptr, ce, bb + i * Dd, bw + (size_t)i * Dd * Dd,
                                   agg16, sS, sQ);
    k_post<<<782, 256, 0, stream>>>(agg16, sS, sQ, bg + i * Dd, bbe + i * Dd,
                                    lw1 + (size_t)(i + 1) * 256, lb1 + (size_t)(i + 1) * 4,
                                    lw2 + (size_t)(i + 1) * 4, lb2 + (i + 1),
                                    fused, h16, (i + 1 < LL) ? 1 : 2);
  }

  k_outmap<<<782, 256, 0, stream>>>(h16, om_w1, om_b1, om_w2, om_b2, out);
}

// Round 6
// 594.610 us; speedup vs baseline: 3.4020x; 1.1496x over previous
//
#include <hip/hip_runtime.h>
#include <math.h>

#define Nn 50000
#define Ee 800000
#define ETe 850000   // E + N self loops
#define Dd 64
#define FIN 128
#define LL 8

typedef _Float16 f16;
typedef f16 f16x8 __attribute__((ext_vector_type(8)));
typedef float f32x4 __attribute__((ext_vector_type(4)));

// ---------------- graph build ----------------

__global__ __launch_bounds__(256) void k_deg(const int* __restrict__ ei, int* __restrict__ deg) {
  int e = blockIdx.x * 256 + threadIdx.x;
  if (e >= ETe) return;
  int dst = (e < Ee) ? ei[Ee + e] : (e - Ee);
  atomicAdd(&deg[dst], 1);
}

__global__ __launch_bounds__(1024) void k_scan(const int* __restrict__ deg, int* __restrict__ rowptr) {
  __shared__ int wsum[16];
  int tid = threadIdx.x;
  int lane = tid & 63, wid = tid >> 6;
  int carry = 0;
  for (int base = 0; base < Nn; base += 1024) {
    int i = base + tid;
    int v = (i < Nn) ? deg[i] : 0;
    int s = v;
    #pragma unroll
    for (int off = 1; off < 64; off <<= 1) {
      int t = __shfl_up(s, off, 64);
      if (lane >= off) s += t;
    }
    if (lane == 63) wsum[wid] = s;
    __syncthreads();
    if (wid == 0) {
      int ws = (lane < 16) ? wsum[lane] : 0;
      #pragma unroll
      for (int off = 1; off < 16; off <<= 1) {
        int t = __shfl_up(ws, off, 64);
        if (lane >= off) ws += t;
      }
      if (lane < 16) wsum[lane] = ws;
    }
    __syncthreads();
    int wexcl = (wid == 0) ? 0 : wsum[wid - 1];
    if (i < Nn) rowptr[i + 1] = carry + wexcl + s;
    carry += wsum[15];
    __syncthreads();
  }
  if (tid == 0) rowptr[0] = 0;
}

__global__ __launch_bounds__(256) void k_dinv(const int* __restrict__ rowptr, float* __restrict__ dinv) {
  int n = blockIdx.x * 256 + threadIdx.x;
  if (n >= Nn) return;
  int d = rowptr[n + 1] - rowptr[n];   // >= 1 (self loop)
  dinv[n] = rsqrtf((float)d);
}

__global__ __launch_bounds__(256) void k_fill(const int* __restrict__ ei, const int* __restrict__ rowptr,
                                              int* __restrict__ fill, const float* __restrict__ dinv,
                                              int2* __restrict__ ce) {
  int e = blockIdx.x * 256 + threadIdx.x;
  if (e >= ETe) return;
  int src, dst;
  if (e < Ee) { src = ei[e]; dst = ei[Ee + e]; }
  else { src = e - Ee; dst = src; }
  int pos = rowptr[dst] + atomicAdd(&fill[dst], 1);
  float w = dinv[src] * dinv[dst];
  ce[pos] = make_int2(src, __float_as_int(w));
}

// ---------------- input map: t = x @ W1 + b1 (MFMA, A from global) + BN stats ----------------

__global__ __launch_bounds__(256) void k_ingemm(const float* __restrict__ x,
    const float* __restrict__ W1, const float* __restrict__ b1,
    f16* __restrict__ t, float* __restrict__ statS, float* __restrict__ statQ) {
  __shared__ __attribute__((aligned(16))) f16 wt[128 * 136];  // wt[n][k] = W1[k][n]
  __shared__ float red[256];
  int tid = threadIdx.x, lane = tid & 63, wid = tid >> 6;
  int row0 = blockIdx.x * 64;
  red[tid] = 0.f;
  // stage wt via k-gather: thread handles (n, kb8), 8 coalesced loads -> one f16x8 write
  for (int i = tid; i < 2048; i += 256) {
    int n = i & 127, kb8 = i >> 7;   // kb8 0..15
    float tmp[8];
    #pragma unroll
    for (int j = 0; j < 8; ++j) tmp[j] = W1[(kb8 * 8 + j) * FIN + n];
    f16x8 v;
    #pragma unroll
    for (int j = 0; j < 8; ++j) v[j] = (f16)tmp[j];
    *(f16x8*)&wt[n * 136 + kb8 * 8] = v;
  }
  __syncthreads();
  int rl = lane & 15, kb = lane >> 4;
  int arow = row0 + wid * 16 + rl;
  bool rv = arow < Nn;
  f16x8 afr[4];
  #pragma unroll
  for (int ks = 0; ks < 4; ++ks) {
    float4 p0 = make_float4(0.f, 0.f, 0.f, 0.f), p1 = p0;
    if (rv) {
      p0 = *(const float4*)&x[(size_t)arow * FIN + ks * 32 + kb * 8];
      p1 = *(const float4*)&x[(size_t)arow * FIN + ks * 32 + kb * 8 + 4];
    }
    f16x8 a;
    a[0] = (f16)p0.x; a[1] = (f16)p0.y; a[2] = (f16)p0.z; a[3] = (f16)p0.w;
    a[4] = (f16)p1.x; a[5] = (f16)p1.y; a[6] = (f16)p1.z; a[7] = (f16)p1.w;
    afr[ks] = a;
  }
  f32x4 acc[8];
  #pragma unroll
  for (int i = 0; i < 8; ++i) acc[i] = (f32x4)0.f;
  #pragma unroll
  for (int ks = 0; ks < 4; ++ks) {
    #pragma unroll
    for (int ct = 0; ct < 8; ++ct) {
      f16x8 b = *(const f16x8*)&wt[(ct * 16 + rl) * 136 + ks * 32 + kb * 8];
      acc[ct] = __builtin_amdgcn_mfma_f32_16x16x32_f16(afr[ks], b, acc[ct], 0, 0, 0);
    }
  }
  #pragma unroll
  for (int ct = 0; ct < 8; ++ct) {
    int col = ct * 16 + rl;
    float bv = b1[col];
    float ps = 0.f, pq = 0.f;
    #pragma unroll
    for (int r = 0; r < 4; ++r) {
      int row = row0 + wid * 16 + kb * 4 + r;
      float v = acc[ct][r] + bv;
      if (row < Nn) {
        t[(size_t)row * FIN + col] = (f16)v;
        ps += v; pq += v * v;
      }
    }
    ps += __shfl_xor(ps, 16, 64); ps += __shfl_xor(ps, 32, 64);
    pq += __shfl_xor(pq, 16, 64); pq += __shfl_xor(pq, 32, 64);
    if (kb == 0) { atomicAdd(&red[col], ps); atomicAdd(&red[128 + col], pq); }
  }
  __syncthreads();
  if (tid < 128) {
    atomicAdd(&statS[tid], red[tid]);
    atomicAdd(&statQ[tid], red[128 + tid]);
  }
}

// ---------------- input map 2 (MFMA): h0 = relu(bn(t)) @ W2 + b2 ; learner0 ; outputs ----------------

__global__ __launch_bounds__(256) void k_inmap2(
    const f16* __restrict__ t, const float* __restrict__ W2, const float* __restrict__ b2,
    const float* __restrict__ statS, const float* __restrict__ statQ,
    const float* __restrict__ g1, const float* __restrict__ be1,
    const float* __restrict__ lw1p, const float* __restrict__ lb1p,
    const float* __restrict__ lw2p, const float* __restrict__ lb2p,
    float* __restrict__ fused, f16* __restrict__ h16) {
  __shared__ __attribute__((aligned(16))) f16 w2t[64 * 136];  // w2t[n][k] = W2[k][n]
  __shared__ __attribute__((aligned(16))) f16 dT[64 * 72];    // h0 tile for learner
  __shared__ __attribute__((aligned(16))) f16 wt1[16 * 72];   // learner w1 (padded)
  __shared__ float scs[FIN], shs[FIN], sg[64];
  int tid = threadIdx.x, lane = tid & 63, wid = tid >> 6;
  int row0 = blockIdx.x * 64;
  for (int i = tid; i < 1024; i += 256) {
    int n = i & 63, kb8 = i >> 6;   // kb8 0..15
    float tmp[8];
    #pragma unroll
    for (int j = 0; j < 8; ++j) tmp[j] = W2[(kb8 * 8 + j) * Dd + n];
    f16x8 v;
    #pragma unroll
    for (int j = 0; j < 8; ++j) v[j] = (f16)tmp[j];
    *(f16x8*)&w2t[n * 136 + kb8 * 8] = v;
  }
  for (int i = tid; i < 16 * 64; i += 256) {
    int n = i & 15, k = i >> 4;
    wt1[n * 72 + k] = (n < 4) ? (f16)lw1p[k * 4 + n] : (f16)0.f;
  }
  if (tid < FIN) {
    float mu = statS[tid] * (1.f / Nn);
    float var = statQ[tid] * (1.f / Nn) - mu * mu;
    float rs = rsqrtf(var + 1e-5f);
    float scv = g1[tid] * rs;
    scs[tid] = scv; shs[tid] = be1[tid] - mu * scv;
  }
  __syncthreads();
  int rl = lane & 15, kb = lane >> 4;
  int arow = row0 + wid * 16 + rl;
  bool rv = arow < Nn;
  f16x8 afr[4];
  #pragma unroll
  for (int ks = 0; ks < 4; ++ks) {
    f16x8 tv;
    #pragma unroll
    for (int j = 0; j < 8; ++j) tv[j] = (f16)0.f;
    if (rv) tv = *(const f16x8*)(t + (size_t)arow * FIN + ks * 32 + kb * 8);
    f16x8 a;
    #pragma unroll
    for (int j = 0; j < 8; ++j) {
      int c = ks * 32 + kb * 8 + j;
      float v = fmaxf(fmaf((float)tv[j], scs[c], shs[c]), 0.f);
      a[j] = (f16)v;
    }
    afr[ks] = a;
  }
  f32x4 acc[4];
  #pragma unroll
  for (int i = 0; i < 4; ++i) acc[i] = (f32x4)0.f;
  #pragma unroll
  for (int ks = 0; ks < 4; ++ks) {
    #pragma unroll
    for (int ct = 0; ct < 4; ++ct) {
      f16x8 b = *(const f16x8*)&w2t[(ct * 16 + rl) * 136 + ks * 32 + kb * 8];
      acc[ct] = __builtin_amdgcn_mfma_f32_16x16x32_f16(afr[ks], b, acc[ct], 0, 0, 0);
    }
  }
  float b2v[4];
  #pragma unroll
  for (int ct = 0; ct < 4; ++ct) b2v[ct] = b2[ct * 16 + rl];
  #pragma unroll
  for (int ct = 0; ct < 4; ++ct)
    #pragma unroll
    for (int r = 0; r < 4; ++r)
      dT[(wid * 16 + kb * 4 + r) * 72 + ct * 16 + rl] = (f16)(acc[ct][r] + b2v[ct]);
  // learner via MFMA (wave-local)
  f32x4 zacc = (f32x4)0.f;
  #pragma unroll
  for (int ks = 0; ks < 2; ++ks) {
    f16x8 af = *(const f16x8*)&dT[(wid * 16 + rl) * 72 + ks * 32 + kb * 8];
    f16x8 bf = *(const f16x8*)&wt1[rl * 72 + ks * 32 + kb * 8];
    zacc = __builtin_amdgcn_mfma_f32_16x16x32_f16(af, bf, zacc, 0, 0, 0);
  }
  float lb1v = (rl < 4) ? lb1p[rl] : 0.f;
  float lw2v = (rl < 4) ? lw2p[rl] : 0.f;
  float lb2v = lb2p[0];
  #pragma unroll
  for (int r = 0; r < 4; ++r) {
    float z = zacc[r] + lb1v;
    z = (z > 0.f) ? z : 0.2f * z;
    float p = z * lw2v;
    p += __shfl_xor(p, 1, 64);
    p += __shfl_xor(p, 2, 64);
    float sgm = 1.f / (1.f + expf(-(p + lb2v)));
    if (rl == 0) sg[wid * 16 + kb * 4 + r] = sgm;
  }
  #pragma unroll
  for (int r = 0; r < 4; ++r) {
    int rw = row0 + wid * 16 + kb * 4 + r;
    if (rw < Nn) {
      float sgm = sg[wid * 16 + kb * 4 + r];
      #pragma unroll
      for (int ct = 0; ct < 4; ++ct) {
        float hn = (acc[ct][r] + b2v[ct]) * sgm;
        fused[(size_t)rw * Dd + ct * 16 + rl] = hn;
        h16[(size_t)rw * Dd + ct * 16 + rl] = (f16)hn;
      }
    }
  }
}

// ---------------- per-layer: gather (1 row / 8-lane group, 4-deep) + MFMA GEMM + stats ----------------

__global__ __launch_bounds__(512) void k_agg(const f16* __restrict__ h16,
    const int* __restrict__ rowptr, const int2* __restrict__ ce,
    const float* __restrict__ bb, const float* __restrict__ W,
    f16* __restrict__ agg, float* __restrict__ statS, float* __restrict__ statQ) {
  __shared__ __attribute__((aligned(16))) f16 sumt[64 * 72];
  __shared__ __attribute__((aligned(16))) f16 wt[64 * 72];    // wt[n][k] = W[k][n]
  __shared__ float red[128];
  int tid = threadIdx.x, lane = tid & 63, wid = tid >> 6;
  int row0 = blockIdx.x * 64;
  {
    int n = tid & 63, kb8 = tid >> 6;   // kb8 0..7, 512 items exactly
    float tmp[8];
    #pragma unroll
    for (int j = 0; j < 8; ++j) tmp[j] = W[(kb8 * 8 + j) * Dd + n];
    f16x8 v;
    #pragma unroll
    for (int j = 0; j < 8; ++j) v[j] = (f16)tmp[j];
    *(f16x8*)&wt[n * 72 + kb8 * 8] = v;
  }
  if (tid < 128) red[tid] = 0.f;

  int g = lane >> 3, cl = lane & 7;
  int lrow = wid * 8 + g;
  int row = row0 + lrow;
  float a[8];
  #pragma unroll
  for (int c = 0; c < 8; ++c) a[c] = 0.f;
  if (row < Nn) {
    int s0 = rowptr[row], s1 = rowptr[row + 1];
    const int2* ep = ce + s0;
    int n = s1 - s0;
    int2 e0 = ep[0], e1 = ep[1], e2 = ep[2], e3 = ep[3];
    for (int j = 0; j < n; j += 4) {
      int2 f0 = ep[j + 4], f1 = ep[j + 5], f2 = ep[j + 6], f3 = ep[j + 7];
      float w0 = __int_as_float(e0.y);
      float w1 = (j + 1 < n) ? __int_as_float(e1.y) : 0.f;
      float w2 = (j + 2 < n) ? __int_as_float(e2.y) : 0.f;
      float w3 = (j + 3 < n) ? __int_as_float(e3.y) : 0.f;
      unsigned c0 = (unsigned)e0.x;
      unsigned c1 = (j + 1 < n) ? (unsigned)e1.x : 0u;
      unsigned c2 = (j + 2 < n) ? (unsigned)e2.x : 0u;
      unsigned c3 = (j + 3 < n) ? (unsigned)e3.x : 0u;
      f16x8 v0 = *(const f16x8*)(h16 + (size_t)c0 * Dd + cl * 8);
      f16x8 v1 = *(const f16x8*)(h16 + (size_t)c1 * Dd + cl * 8);
      f16x8 v2 = *(const f16x8*)(h16 + (size_t)c2 * Dd + cl * 8);
      f16x8 v3 = *(const f16x8*)(h16 + (size_t)c3 * Dd + cl * 8);
      #pragma unroll
      for (int c = 0; c < 8; ++c) a[c] = fmaf(w0, (float)v0[c], a[c]);
      #pragma unroll
      for (int c = 0; c < 8; ++c) a[c] = fmaf(w1, (float)v1[c], a[c]);
      #pragma unroll
      for (int c = 0; c < 8; ++c) a[c] = fmaf(w2, (float)v2[c], a[c]);
      #pragma unroll
      for (int c = 0; c < 8; ++c) a[c] = fmaf(w3, (float)v3[c], a[c]);
      e0 = f0; e1 = f1; e2 = f2; e3 = f3;
    }
  }
  f16x8 hv;
  #pragma unroll
  for (int c = 0; c < 8; ++c) hv[c] = (f16)a[c];
  *(f16x8*)&sumt[lrow * 72 + cl * 8] = hv;
  __syncthreads();

  // MFMA: 8 waves; wave = (strip 0..3) x (ct half 0..1)
  int rl = lane & 15, kb = lane >> 4;
  int strip = wid & 3, ch = wid >> 2;
  f32x4 acc0 = (f32x4)0.f, acc1 = (f32x4)0.f;
  #pragma unroll
  for (int ks = 0; ks < 2; ++ks) {
    f16x8 af = *(const f16x8*)&sumt[(strip * 16 + rl) * 72 + ks * 32 + kb * 8];
    f16x8 b0 = *(const f16x8*)&wt[((ch * 2) * 16 + rl) * 72 + ks * 32 + kb * 8];
    f16x8 b1 = *(const f16x8*)&wt[((ch * 2 + 1) * 16 + rl) * 72 + ks * 32 + kb * 8];
    acc0 = __builtin_amdgcn_mfma_f32_16x16x32_f16(af, b0, acc0, 0, 0, 0);
    acc1 = __builtin_amdgcn_mfma_f32_16x16x32_f16(af, b1, acc1, 0, 0, 0);
  }
  #pragma unroll
  for (int t2 = 0; t2 < 2; ++t2) {
    f32x4 ac = t2 ? acc1 : acc0;
    int col = (ch * 2 + t2) * 16 + rl;
    float bv = bb[col];
    float s = 0.f, q = 0.f;
    #pragma unroll
    for (int r = 0; r < 4; ++r) {
      int rw = row0 + strip * 16 + kb * 4 + r;
      float o = ac[r] + bv;
      if (rw < Nn) {
        agg[(size_t)rw * Dd + col] = (f16)o;
        s += o; q += o * o;
      }
    }
    s += __shfl_xor(s, 16, 64); s += __shfl_xor(s, 32, 64);
    q += __shfl_xor(q, 16, 64); q += __shfl_xor(q, 32, 64);
    if (kb == 0) { atomicAdd(&red[col], s); atomicAdd(&red[64 + col], q); }
  }
  __syncthreads();
  if (tid < 64) {
    atomicAdd(&statS[tid], red[tid]);
    atomicAdd(&statQ[tid], red[64 + tid]);
  }
}

// ---------------- post: BN + MFMA learner + gate + residual ----------------

__global__ __launch_bounds__(256) void k_post(const f16* __restrict__ agg,
    const float* __restrict__ statS, const float* __restrict__ statQ,
    const float* __restrict__ gamma, const float* __restrict__ beta,
    const float* __restrict__ lw1p, const float* __restrict__ lb1p,
    const float* __restrict__ lw2p, const float* __restrict__ lb2p,
    float* __restrict__ fused, f16* __restrict__ h16, int mode) {
  __shared__ __attribute__((aligned(16))) f16 dT[64 * 72];   // d = h - fused, [row][ch]
  __shared__ __attribute__((aligned(16))) f16 wt1[16 * 72];  // wt1[n][ch] = lw1[ch][n] (n<4)
  __shared__ float scs[Dd], shs[Dd], sg[64];
  int tid = threadIdx.x, lane = tid & 63, wid = tid >> 6;
  int row0 = blockIdx.x * 64;
  if (tid < Dd) {
    float mu = statS[tid] * (1.f / Nn);
    float var = statQ[tid] * (1.f / Nn) - mu * mu;
    float rs = rsqrtf(var + 1e-5f);
    float scv = gamma[tid] * rs;
    scs[tid] = scv; shs[tid] = beta[tid] - mu * scv;
  }
  for (int i = tid; i < 16 * 64; i += 256) {
    int n = i & 15, k = i >> 4;
    wt1[n * 72 + k] = (n < 4) ? (f16)lw1p[k * 4 + n] : (f16)0.f;
  }
  __syncthreads();
  float sc = scs[lane], sh = shs[lane];
  float hb[16], fv[16];
  #pragma unroll
  for (int r = 0; r < 16; ++r) {
    int row = row0 + wid * 16 + r;
    float a = 0.f, f = 0.f;
    if (row < Nn) {
      a = (float)agg[(size_t)row * Dd + lane];
      f = fused[(size_t)row * Dd + lane];
    }
    float h = fmaxf(fmaf(a, sc, sh), 0.f);
    hb[r] = h; fv[r] = f;
    dT[(wid * 16 + r) * 72 + lane] = (f16)(h - f);
  }
  int rl = lane & 15, kb = lane >> 4;
  f32x4 zacc = (f32x4)0.f;
  #pragma unroll
  for (int ks = 0; ks < 2; ++ks) {
    f16x8 af = *(const f16x8*)&dT[(wid * 16 + rl) * 72 + ks * 32 + kb * 8];
    f16x8 bf = *(const f16x8*)&wt1[rl * 72 + ks * 32 + kb * 8];
    zacc = __builtin_amdgcn_mfma_f32_16x16x32_f16(af, bf, zacc, 0, 0, 0);
  }
  float lb1v = (rl < 4) ? lb1p[rl] : 0.f;
  float lw2v = (rl < 4) ? lw2p[rl] : 0.f;
  float lb2v = lb2p[0];
  #pragma unroll
  for (int r = 0; r < 4; ++r) {
    float z = zacc[r] + lb1v;
    z = (z > 0.f) ? z : 0.2f * z;
    float p = z * lw2v;
    p += __shfl_xor(p, 1, 64);
    p += __shfl_xor(p, 2, 64);
    float sgm = 1.f / (1.f + expf(-(p + lb2v)));
    if (rl == 0) sg[wid * 16 + kb * 4 + r] = sgm;
  }
  #pragma unroll
  for (int r = 0; r < 16; ++r) {
    int row = row0 + wid * 16 + r;
    if (row < Nn) {
      float sgm = sg[wid * 16 + r];
      float hn = hb[r] * sgm;
      float fn = fv[r] + hn;
      fused[(size_t)row * Dd + lane] = fn;
      h16[(size_t)row * Dd + lane] = (f16)((mode == 1) ? hn : fn);
    }
  }
}

// ---------------- output map (MFMA, both GEMMs fused) ----------------

__global__ __launch_bounds__(256) void k_outmap(const f16* __restrict__ fused16,
    const float* __restrict__ W1, const float* __restrict__ b1,
    const float* __restrict__ W2, const float* __restrict__ b2, float* __restrict__ out) {
  __shared__ __attribute__((aligned(16))) f16 fs[64 * 72];    // A tile [row][k<64]
  __shared__ __attribute__((aligned(16))) f16 w1t[128 * 72];  // w1t[n][k] = W1[k][n]
  __shared__ __attribute__((aligned(16))) f16 w2t[64 * 136];  // w2t[n][k] = W2[k][n]
  __shared__ __attribute__((aligned(16))) f16 zs[64 * 136];   // z rows [row][k<128]
  int tid = threadIdx.x, lane = tid & 63, wid = tid >> 6;
  int row0 = blockIdx.x * 64;
  for (int i = tid; i < 64 * 64; i += 256) {
    int r = i >> 6, c = i & 63;
    fs[r * 72 + c] = (row0 + r < Nn) ? fused16[(size_t)(row0 + r) * Dd + c] : (f16)0.f;
  }
  for (int i = tid; i < 64 * 128; i += 256) {
    int k = i >> 7, n = i & 127;
    w1t[n * 72 + k] = (f16)W1[i];
  }
  for (int i = tid; i < 128 * 64; i += 256) {
    int k = i >> 6, n = i & 63;
    w2t[n * 136 + k] = (f16)W2[i];
  }
  __syncthreads();
  int rl = lane & 15, kb = lane >> 4;
  f32x4 acc1[8];
  #pragma unroll
  for (int i = 0; i < 8; ++i) acc1[i] = (f32x4)0.f;
  #pragma unroll
  for (int ks = 0; ks < 2; ++ks) {
    f16x8 a = *(const f16x8*)&fs[(wid * 16 + rl) * 72 + ks * 32 + kb * 8];
    #pragma unroll
    for (int ct = 0; ct < 8; ++ct) {
      f16x8 b = *(const f16x8*)&w1t[(ct * 16 + rl) * 72 + ks * 32 + kb * 8];
      acc1[ct] = __builtin_amdgcn_mfma_f32_16x16x32_f16(a, b, acc1[ct], 0, 0, 0);
    }
  }
  #pragma unroll
  for (int ct = 0; ct < 8; ++ct) {
    float bv = b1[ct * 16 + rl];
    #pragma unroll
    for (int r = 0; r < 4; ++r) {
      float z = fmaxf(acc1[ct][r] + bv, 0.f);
      zs[(wid * 16 + kb * 4 + r) * 136 + ct * 16 + rl] = (f16)z;
    }
  }
  __syncthreads();
  f32x4 acc2[4];
  #pragma unroll
  for (int i = 0; i < 4; ++i) acc2[i] = (f32x4)0.f;
  #pragma unroll
  for (int ks = 0; ks < 4; ++ks) {
    f16x8 a = *(const f16x8*)&zs[(wid * 16 + rl) * 136 + ks * 32 + kb * 8];
    #pragma unroll
    for (int ct = 0; ct < 4; ++ct) {
      f16x8 b = *(const f16x8*)&w2t[(ct * 16 + rl) * 136 + ks * 32 + kb * 8];
      acc2[ct] = __builtin_amdgcn_mfma_f32_16x16x32_f16(a, b, acc2[ct], 0, 0, 0);
    }
  }
  #pragma unroll
  for (int ct = 0; ct < 4; ++ct) {
    float bv = b2[ct * 16 + rl];
    #pragma unroll
    for (int r = 0; r < 4; ++r) {
      int row = row0 + wid * 16 + kb * 4 + r;
      if (row < Nn) out[(size_t)row * Dd + ct * 16 + rl] = acc2[ct][r] + bv;
    }
  }
}

// ---------------- launch ----------------

extern "C" void kernel_launch(void* const* d_in, const int* in_sizes, int n_in,
                              void* d_out, int out_size, void* d_ws, size_t ws_size,
                              hipStream_t stream) {
  const float* x      = (const float*)d_in[0];
  const int*   ei     = (const int*)d_in[1];
  const float* im_w1  = (const float*)d_in[2];
  const float* im_b1  = (const float*)d_in[3];
  const float* im_g1  = (const float*)d_in[4];
  const float* im_be1 = (const float*)d_in[5];
  const float* im_w2  = (const float*)d_in[6];
  const float* im_b2  = (const float*)d_in[7];
  const float* lw1    = (const float*)d_in[8];
  const float* lb1    = (const float*)d_in[9];
  const float* lw2    = (const float*)d_in[10];
  const float* lb2    = (const float*)d_in[11];
  const float* bw     = (const float*)d_in[12];
  const float* bb     = (const float*)d_in[13];
  const float* bg     = (const float*)d_in[14];
  const float* bbe    = (const float*)d_in[15];
  const float* om_w1  = (const float*)d_in[16];
  const float* om_b1  = (const float*)d_in[17];
  const float* om_w2  = (const float*)d_in[18];
  const float* om_b2  = (const float*)d_in[19];
  float* out = (float*)d_out;

  char* w = (char*)d_ws;
  size_t off = 0;
  auto alloc = [&](size_t bytes) -> void* {
    void* p = w + off;
    off = (off + bytes + 255) & ~(size_t)255;
    return p;
  };
  // zeroed region first
  int*   deg    = (int*)alloc((size_t)Nn * 4);
  int*   fill   = (int*)alloc((size_t)Nn * 4);
  float* statS  = (float*)alloc((size_t)9 * 128 * 4);
  float* statQ  = (float*)alloc((size_t)9 * 128 * 4);
  size_t zero_bytes = off;
  int*   rowptr = (int*)alloc((size_t)(Nn + 1) * 4);
  int2*  ce     = (int2*)alloc((size_t)(ETe + 8) * 8);   // +pad for 4-deep prefetch
  float* dinv   = (float*)alloc((size_t)Nn * 4);
  f16*   t      = (f16*)alloc((size_t)Nn * FIN * 2);
  f16*   h16    = (f16*)alloc((size_t)Nn * Dd * 2);
  f16*   agg16  = (f16*)alloc((size_t)Nn * Dd * 2);
  float* fused  = (float*)alloc((size_t)Nn * Dd * 4);
  (void)deg; (void)fill;

  hipMemsetAsync(d_ws, 0, zero_bytes, stream);
  k_deg<<<(ETe + 255) / 256, 256, 0, stream>>>(ei, deg);
  k_scan<<<1, 1024, 0, stream>>>(deg, rowptr);
  k_dinv<<<(Nn + 255) / 256, 256, 0, stream>>>(rowptr, dinv);
  k_fill<<<(ETe + 255) / 256, 256, 0, stream>>>(ei, rowptr, fill, dinv, ce);

  k_ingemm<<<782, 256, 0, stream>>>(x, im_w1, im_b1, t, statS, statQ);
  k_inmap2<<<782, 256, 0, stream>>>(t, im_w2, im_b2, statS, statQ, im_g1, im_be1,
                                    lw1, lb1, lw2, lb2, fused, h16);

  for (int i = 0; i < LL; ++i) {
    float* sS = statS + (size_t)(1 + i) * 128;
    float* sQ = statQ + (size_t)(1 + i) * 128;
    k_agg<<<782, 512, 0, stream>>>(h16, rowptr, ce, bb + i * Dd, bw + (size_t)i * Dd * Dd,
                                   agg16, sS, sQ);
    k_post<<<782, 256, 0, stream>>>(agg16, sS, sQ, bg + i * Dd, bbe + i * Dd,
                                    lw1 + (size_t)(i + 1) * 256, lb1 + (size_t)(i + 1) * 4,
                                    lw2 + (size_t)(i + 1) * 4, lb2 + (i + 1),
                                    fused, h16, (i + 1 < LL) ? 1 : 2);
  }

  k_outmap<<<782, 256, 0, stream>>>(h16, om_w1, om_b1, om_w2, om_b2, out);
}